// Round 1
// baseline (2610.483 us; speedup 1.0000x reference)
//
#include <hip/hip_runtime.h>
#include <hip/hip_bf16.h>

// Problem constants
#define NEGV -1e30f
// B=64, N=16, T=64, D=128, H=256, M=17 (N+1 slots), O=1

__device__ __forceinline__ float sigmoidf_(float x) {
    return 1.0f / (1.0f + __expf(-x));
}
__device__ __forceinline__ float tanhf_(float x) {
    float ax = fabsf(x);
    float e = __expf(-2.0f * ax);
    float t = (1.0f - e) / (1.0f + e);
    return copysignf(t, x);
}

// ---------------------------------------------------------------------------
// Generic 64x64-tile fp32 GEMM: C = A @ B (with optional transposes) + bias.
//   A: (M,K) row-major (or (K,M) if transA), fp32 or bf16
//   B: (K,N) row-major, or (N,K) if transB (i.e. C = A @ B^T)
//   outmode 0: C[row*N+col]
//   outmode 1: node->slot0 layout  C[(b*1088 + s)*256 + col],  b=row/64, s=row%64
//   outmode 2: ngh ->slot n+1      C[(b*1088 + (n+1)*64 + s)*256 + col]
// ---------------------------------------------------------------------------
__global__ __launch_bounds__(256) void gemm64(
    const void* __restrict__ Av, const float* __restrict__ Bm,
    const float* __restrict__ bias, void* __restrict__ Cv,
    int M, int N, int K,
    int a_bf16, int transA, int transB, int c_bf16, int outmode)
{
    __shared__ __align__(16) float As[32 * 68];
    __shared__ __align__(16) float Bs[32 * 68];
    const int tid = threadIdx.x;
    const int tx = tid & 15, ty = tid >> 4;
    const int rb = blockIdx.x * 64, cb = blockIdx.y * 64;
    const float* Af = (const float*)Av;
    const __hip_bfloat16* Ah = (const __hip_bfloat16*)Av;
    float acc[4][4] = {};
    for (int k0 = 0; k0 < K; k0 += 32) {
        __syncthreads();
        if (!transA) {
            for (int f = tid; f < 2048; f += 256) {
                int r = f >> 5, kk = f & 31;
                size_t g = (size_t)(rb + r) * K + (k0 + kk);
                As[kk * 68 + r] = a_bf16 ? (float)Ah[g] : Af[g];
            }
        } else {
            for (int f = tid; f < 2048; f += 256) {
                int kk = f >> 6, r = f & 63;
                As[kk * 68 + r] = Af[(size_t)(k0 + kk) * M + (rb + r)];
            }
        }
        if (transB) {
            for (int f = tid; f < 2048; f += 256) {
                int c = f >> 5, kk = f & 31;
                Bs[kk * 68 + c] = Bm[(size_t)(cb + c) * K + (k0 + kk)];
            }
        } else {
            for (int f = tid; f < 2048; f += 256) {
                int kk = f >> 6, c = f & 63;
                Bs[kk * 68 + c] = Bm[(size_t)(k0 + kk) * N + (cb + c)];
            }
        }
        __syncthreads();
#pragma unroll
        for (int kk = 0; kk < 32; ++kk) {
            float4 a4 = *(const float4*)(As + kk * 68 + ty * 4);
            float4 b4 = *(const float4*)(Bs + kk * 68 + tx * 4);
            float av[4] = {a4.x, a4.y, a4.z, a4.w};
            float bv[4] = {b4.x, b4.y, b4.z, b4.w};
#pragma unroll
            for (int i = 0; i < 4; ++i)
#pragma unroll
                for (int j = 0; j < 4; ++j)
                    acc[i][j] += av[i] * bv[j];
        }
    }
#pragma unroll
    for (int i = 0; i < 4; ++i) {
        int row = rb + ty * 4 + i;
#pragma unroll
        for (int j = 0; j < 4; ++j) {
            int col = cb + tx * 4 + j;
            float v = acc[i][j];
            if (bias) v += bias[col];
            size_t oidx;
            if (outmode == 0) {
                oidx = (size_t)row * N + col;
            } else if (outmode == 1) {
                int bb = row >> 6, s = row & 63;
                oidx = ((size_t)bb * 1088 + s) * 256 + col;
            } else {
                int rr = row >> 6, s = row & 63;
                int bb = rr >> 4, nn = rr & 15;
                oidx = ((size_t)bb * 1088 + (nn + 1) * 64 + s) * 256 + col;
            }
            if (c_bf16) ((__hip_bfloat16*)Cv)[oidx] = (__hip_bfloat16)v;
            else        ((float*)Cv)[oidx] = v;
        }
    }
}

// ---------------------------------------------------------------------------
// Recurrent GEMM: gh(1088x768) = h_old(1088x256) @ Whh^T. Rows 0..63 use the
// node weights (row-tiles 0,1), rows 64..1087 the neighbor weights.
// Tiles 32x64, grid (34,12).
// ---------------------------------------------------------------------------
__global__ __launch_bounds__(256) void gh_gemm(
    const float* __restrict__ h_old,
    const float* __restrict__ Whh_node, const float* __restrict__ Whh_ngh,
    float* __restrict__ gh)
{
    __shared__ __align__(16) float As[32 * 34];
    __shared__ __align__(16) float Bs[32 * 68];
    const int tid = threadIdx.x;
    const int tx = tid & 15, ty = tid >> 4;
    const int rb = blockIdx.x * 32, cb = blockIdx.y * 64;
    const float* W = (blockIdx.x < 2) ? Whh_node : Whh_ngh;
    float acc[2][4] = {};
    for (int k0 = 0; k0 < 256; k0 += 32) {
        __syncthreads();
        for (int f = tid; f < 1024; f += 256) {
            int r = f >> 5, kk = f & 31;
            As[kk * 34 + r] = h_old[(size_t)(rb + r) * 256 + (k0 + kk)];
        }
        for (int f = tid; f < 2048; f += 256) {
            int c = f >> 5, kk = f & 31;
            Bs[kk * 68 + c] = W[(size_t)(cb + c) * 256 + (k0 + kk)];
        }
        __syncthreads();
#pragma unroll
        for (int kk = 0; kk < 32; ++kk) {
            float2 a2 = *(const float2*)(As + kk * 34 + ty * 2);
            float4 b4 = *(const float4*)(Bs + kk * 68 + tx * 4);
            float av[2] = {a2.x, a2.y};
            float bv[4] = {b4.x, b4.y, b4.z, b4.w};
#pragma unroll
            for (int i = 0; i < 2; ++i)
#pragma unroll
                for (int j = 0; j < 4; ++j)
                    acc[i][j] += av[i] * bv[j];
        }
    }
#pragma unroll
    for (int i = 0; i < 2; ++i) {
        int row = rb + ty * 2 + i;
#pragma unroll
        for (int j = 0; j < 4; ++j)
            gh[(size_t)row * 768 + cb + tx * 4 + j] = acc[i][j];
    }
}

// ---------------------------------------------------------------------------
// GRU gate pointwise for step t. 1088 rows x 256 hidden.
//  r = sig(gi_r + gh_r + bhh_r); z = sig(gi_z + gh_z + bhh_z)
//  n = tanh(gi_n + r*(gh_n + bhh_n)); h' = (1-z)n + z h
// gi already contains bih. Writes h_new and the sequence outputs.
// ---------------------------------------------------------------------------
__global__ __launch_bounds__(256) void gru_pointwise(
    const float* __restrict__ h_old, float* __restrict__ h_new,
    const float* __restrict__ gh, const __hip_bfloat16* __restrict__ gi,
    const float* __restrict__ bhh_node, const float* __restrict__ bhh_ngh,
    float* __restrict__ node_out, __hip_bfloat16* __restrict__ ngh_out, int t)
{
    int idx = blockIdx.x * 256 + threadIdx.x;   // < 1088*256
    int r = idx >> 8, j = idx & 255;
    const float* bhh = (r < 64) ? bhh_node : bhh_ngh;
    size_t girow = (r < 64) ? ((size_t)r * 64 + t)
                            : (4096 + (size_t)(r - 64) * 64 + t);
    const __hip_bfloat16* g = gi + girow * 768;
    float gir = (float)g[j], giz = (float)g[256 + j], gin = (float)g[512 + j];
    const float* ghrow = gh + (size_t)r * 768;
    float ghr = ghrow[j]       + bhh[j];
    float ghz = ghrow[256 + j] + bhh[256 + j];
    float ghn = ghrow[512 + j] + bhh[512 + j];
    float rg = sigmoidf_(gir + ghr);
    float zg = sigmoidf_(giz + ghz);
    float ng = tanhf_(gin + rg * ghn);
    float hp = h_old[idx];
    float hn = (1.0f - zg) * ng + zg * hp;
    h_new[idx] = hn;
    if (r < 64) node_out[((size_t)r * 64 + t) * 256 + j] = hn;
    else        ngh_out[((size_t)(r - 64) * 64 + t) * 256 + j] = (__hip_bfloat16)hn;
}

// ---------------------------------------------------------------------------
// Fused attention per (b,m): S = Qb@K^T (+bbil, causal mask) -> softmax (A to
// d_out) -> ctx = A@V -> per-t projection dot(ctx, Wprj) -> atomicAdd out[b,t].
// ---------------------------------------------------------------------------
__global__ __launch_bounds__(256) void attn_kernel(
    const float* __restrict__ Qb, const __hip_bfloat16* __restrict__ Kb,
    const __hip_bfloat16* __restrict__ Vb, const float* __restrict__ bbil,
    const float* __restrict__ Wprj, const float* __restrict__ bprj,
    float* __restrict__ A_out, float* __restrict__ out)
{
    __shared__ __align__(16) float Sbuf[64 * 68];
    __shared__ __align__(16) float Stage[64 * 68];  // QTs|KTs in phase 1, V tile in phase 2
    __shared__ float rowmax[64], rowrcp[64];
    __shared__ float red[1024];
    const int tid = threadIdx.x;
    const int tx = tid & 15, ty = tid >> 4;
    const int bm = blockIdx.x;
    const int b = bm / 17, m = bm % 17;
    const float* Qrow = Qb + (size_t)b * 64 * 256;
    const __hip_bfloat16* Krow = Kb + ((size_t)b * 1088 + m * 64) * 256;
    const __hip_bfloat16* Vrow = Vb + ((size_t)b * 1088 + m * 64) * 256;

    // --- S = Qb @ K^T ---
    float acc[4][4] = {};
    for (int k0 = 0; k0 < 256; k0 += 32) {
        __syncthreads();
        for (int f = tid; f < 2048; f += 256) {
            int r = f >> 5, kk = f & 31;
            Stage[kk * 68 + r] = Qrow[(size_t)r * 256 + (k0 + kk)];
        }
        for (int f = tid; f < 2048; f += 256) {
            int s = f >> 5, kk = f & 31;
            Stage[2176 + kk * 68 + s] = (float)Krow[(size_t)s * 256 + (k0 + kk)];
        }
        __syncthreads();
#pragma unroll
        for (int kk = 0; kk < 32; ++kk) {
            float4 a4 = *(const float4*)(Stage + kk * 68 + ty * 4);
            float4 b4 = *(const float4*)(Stage + 2176 + kk * 68 + tx * 4);
            float av[4] = {a4.x, a4.y, a4.z, a4.w};
            float bv[4] = {b4.x, b4.y, b4.z, b4.w};
#pragma unroll
            for (int i = 0; i < 4; ++i)
#pragma unroll
                for (int j = 0; j < 4; ++j)
                    acc[i][j] += av[i] * bv[j];
        }
    }
    __syncthreads();
#pragma unroll
    for (int i = 0; i < 4; ++i)
#pragma unroll
        for (int j = 0; j < 4; ++j) {
            int t = ty * 4 + i, s = tx * 4 + j;
            Sbuf[t * 68 + s] = (s <= t) ? (acc[i][j] + bbil[s]) : NEGV;
        }
    __syncthreads();
    // --- softmax stats ---
    if (tid < 64) {
        float mx = -3.0e38f;
        for (int s = 0; s < 64; ++s) mx = fmaxf(mx, Sbuf[tid * 68 + s]);
        float sum = 0.0f;
        for (int s = 0; s < 64; ++s) sum += __expf(Sbuf[tid * 68 + s] - mx);
        rowmax[tid] = mx;
        rowrcp[tid] = 1.0f / sum;
    }
    __syncthreads();
    // --- write A (coalesced) and keep it in LDS ---
    for (int idx = tid; idx < 4096; idx += 256) {
        int t = idx >> 6, s = idx & 63;
        float e = __expf(Sbuf[t * 68 + s] - rowmax[t]) * rowrcp[t];
        A_out[(size_t)bm * 4096 + idx] = e;
        Sbuf[t * 68 + s] = e;
    }
    // --- ctx = A @ V, fused with projection onto Wprj ---
    float partial[4] = {0.f, 0.f, 0.f, 0.f};
    for (int hq = 0; hq < 4; ++hq) {
        __syncthreads();
        for (int f = tid; f < 4096; f += 256) {
            int s = f >> 6, c = f & 63;
            Stage[s * 68 + c] = (float)Vrow[(size_t)s * 256 + hq * 64 + c];
        }
        __syncthreads();
        float cacc[4][4] = {};
#pragma unroll 4
        for (int kk = 0; kk < 64; ++kk) {
            float a0 = Sbuf[(ty * 4 + 0) * 68 + kk];
            float a1 = Sbuf[(ty * 4 + 1) * 68 + kk];
            float a2 = Sbuf[(ty * 4 + 2) * 68 + kk];
            float a3 = Sbuf[(ty * 4 + 3) * 68 + kk];
            float4 b4 = *(const float4*)(Stage + kk * 68 + tx * 4);
            float bv[4] = {b4.x, b4.y, b4.z, b4.w};
#pragma unroll
            for (int j = 0; j < 4; ++j) {
                cacc[0][j] += a0 * bv[j];
                cacc[1][j] += a1 * bv[j];
                cacc[2][j] += a2 * bv[j];
                cacc[3][j] += a3 * bv[j];
            }
        }
#pragma unroll
        for (int i = 0; i < 4; ++i)
#pragma unroll
            for (int j = 0; j < 4; ++j)
                partial[i] += cacc[i][j] * Wprj[hq * 64 + tx * 4 + j];
    }
#pragma unroll
    for (int i = 0; i < 4; ++i) red[(ty * 4 + i) * 16 + tx] = partial[i];
    __syncthreads();
    if (tid < 64) {
        float s = 0.0f;
#pragma unroll
        for (int q = 0; q < 16; ++q) s += red[tid * 16 + q];
        if (m == 0) s += 17.0f * bprj[0];
        atomicAdd(out + b * 64 + tid, s);
    }
}

// ---------------------------------------------------------------------------
extern "C" void kernel_launch(void* const* d_in, const int* in_sizes, int n_in,
                              void* d_out, int out_size, void* d_ws, size_t ws_size,
                              hipStream_t stream)
{
    const float* node_input       = (const float*)d_in[0];
    const float* node_hidden      = (const float*)d_in[1];
    const float* neighbors_input  = (const float*)d_in[2];
    const float* neighbors_hidden = (const float*)d_in[3];
    // d_in[4] = s_len (unused by the reference)
    const float* Wih_node = (const float*)d_in[5];
    const float* Whh_node = (const float*)d_in[6];
    const float* bih_node = (const float*)d_in[7];
    const float* bhh_node = (const float*)d_in[8];
    const float* Wih_ngh  = (const float*)d_in[9];
    const float* Whh_ngh  = (const float*)d_in[10];
    const float* bih_ngh  = (const float*)d_in[11];
    const float* bhh_ngh  = (const float*)d_in[12];
    const float* Wq   = (const float*)d_in[13];
    const float* Wk   = (const float*)d_in[14];
    const float* Wv   = (const float*)d_in[15];
    const float* Wbil = (const float*)d_in[16];
    const float* bbil = (const float*)d_in[17];
    const float* Wprj = (const float*)d_in[18];
    const float* bprj = (const float*)d_in[19];

    float* out         = (float*)d_out;          // (B,T)            4096
    float* out_node_hT = out + 4096;             // (1,B,H)          16384
    float* out_ngh_hT  = out + 20480;            // (1,B*N,H)        262144
    float* out_A       = out + 282624;           // (B,17,T,T)       4456448

    // workspace layout (fp32 region then bf16 region); ~155 MB total
    float* hbuf0    = (float*)d_ws;              // 1088*256
    float* hbuf1    = hbuf0 + 278528;
    float* gh       = hbuf1 + 278528;            // 1088*768
    float* node_out = gh + 835584;               // 4096*256
    float* wqb      = node_out + 1048576;        // 256*256
    float* qb       = wqb + 65536;               // 4096*256
    __hip_bfloat16* ngh_out = (__hip_bfloat16*)(qb + 1048576);  // 65536*256
    __hip_bfloat16* gi      = ngh_out + 16777216;               // 69632*768
    __hip_bfloat16* kbuf    = gi;                 // reuse gi region after scan
    __hip_bfloat16* vbuf    = kbuf + 17825792;    // 69632*256 each

    hipMemsetAsync(d_out, 0, 4096 * sizeof(float), stream);
    hipMemcpyAsync(hbuf0, node_hidden, 16384 * sizeof(float),
                   hipMemcpyDeviceToDevice, stream);
    hipMemcpyAsync(hbuf0 + 16384, neighbors_hidden, 262144 * sizeof(float),
                   hipMemcpyDeviceToDevice, stream);

    // gi = x @ Wih^T + bih for all timesteps (both GRUs), stored bf16
    gemm64<<<dim3(64, 12), 256, 0, stream>>>(node_input, Wih_node, bih_node,
        gi, 4096, 768, 128, 0, 0, 1, 1, 0);
    gemm64<<<dim3(1024, 12), 256, 0, stream>>>(neighbors_input, Wih_ngh, bih_ngh,
        gi + (size_t)4096 * 768, 65536, 768, 128, 0, 0, 1, 1, 0);

    // sequential GRU scan (node rows 0..63, neighbor rows 64..1087)
    for (int t = 0; t < 64; ++t) {
        const float* hold = (t & 1) ? hbuf1 : hbuf0;
        float*       hnew = (t & 1) ? hbuf0 : hbuf1;
        gh_gemm<<<dim3(34, 12), 256, 0, stream>>>(hold, Whh_node, Whh_ngh, gh);
        gru_pointwise<<<1088, 256, 0, stream>>>(hold, hnew, gh, gi,
            bhh_node, bhh_ngh, node_out, ngh_out, t);
    }
    // final hidden states (t=63 wrote hbuf0)
    hipMemcpyAsync(out_node_hT, hbuf0, 16384 * sizeof(float),
                   hipMemcpyDeviceToDevice, stream);
    hipMemcpyAsync(out_ngh_hT, hbuf0 + 16384, 262144 * sizeof(float),
                   hipMemcpyDeviceToDevice, stream);

    // wqb = Wq^T @ Wbil  (fold Q and bilinear projections)
    gemm64<<<dim3(4, 4), 256, 0, stream>>>(Wq, Wbil, nullptr, wqb,
        256, 256, 256, 0, 1, 0, 0, 0);
    // Qb = node_out @ wqb
    gemm64<<<dim3(64, 4), 256, 0, stream>>>(node_out, wqb, nullptr, qb,
        4096, 256, 256, 0, 0, 0, 0, 0);
    // K = kv @ Wk^T  (slot-mapped layout, bf16)
    gemm64<<<dim3(64, 4), 256, 0, stream>>>(node_out, Wk, nullptr, kbuf,
        4096, 256, 256, 0, 0, 1, 1, 1);
    gemm64<<<dim3(1024, 4), 256, 0, stream>>>(ngh_out, Wk, nullptr, kbuf,
        65536, 256, 256, 1, 0, 1, 1, 2);
    // V = kv @ Wv^T
    gemm64<<<dim3(64, 4), 256, 0, stream>>>(node_out, Wv, nullptr, vbuf,
        4096, 256, 256, 0, 0, 1, 1, 1);
    gemm64<<<dim3(1024, 4), 256, 0, stream>>>(ngh_out, Wv, nullptr, vbuf,
        65536, 256, 256, 1, 0, 1, 1, 2);

    // fused S/softmax/A/ctx/projection
    attn_kernel<<<1088, 256, 0, stream>>>(qb, kbuf, vbuf, bbil, Wprj, bprj,
                                          out_A, out);
}

// Round 2
// 755.125 us; speedup vs baseline: 3.4570x; 3.4570x over previous
//
#include <hip/hip_runtime.h>
#include <hip/hip_bf16.h>

#define NEGV -1e30f
typedef __attribute__((ext_vector_type(8))) short bf16x8;
typedef __attribute__((ext_vector_type(4))) float f32x4;

__device__ __forceinline__ float sigmoidf_(float x) { return 1.0f / (1.0f + __expf(-x)); }
__device__ __forceinline__ float tanhf_(float x) {
    float ax = fabsf(x);
    float e = __expf(-2.0f * ax);
    float t = (1.0f - e) / (1.0f + e);
    return copysignf(t, x);
}
__device__ __forceinline__ float bf2f(unsigned short u) {
    union { float f; unsigned int i; } x; x.i = ((unsigned int)u) << 16; return x.f;
}

// ---------------------------------------------------------------------------
// Small fp32 GEMM for wqb_t[h'][d] = sum_k Wbil[k][h'] * Wq[k][d]  (256x256)
// ---------------------------------------------------------------------------
__global__ __launch_bounds__(256) void wqb_gemm(const float* __restrict__ Wbil_,
    const float* __restrict__ Wq_, float* __restrict__ outw)
{
    __shared__ __align__(16) float As[32 * 68];
    __shared__ __align__(16) float Bs[32 * 68];
    const int tid = threadIdx.x, tx = tid & 15, ty = tid >> 4;
    const int rb = blockIdx.x * 64, cb = blockIdx.y * 64;
    float acc[4][4] = {};
    for (int k0 = 0; k0 < 256; k0 += 32) {
        __syncthreads();
        for (int f = tid; f < 2048; f += 256) {
            int kk = f >> 6, r = f & 63;
            As[kk * 68 + r] = Wbil_[(size_t)(k0 + kk) * 256 + rb + r];
        }
        for (int f = tid; f < 2048; f += 256) {
            int kk = f >> 6, c = f & 63;
            Bs[kk * 68 + c] = Wq_[(size_t)(k0 + kk) * 256 + cb + c];
        }
        __syncthreads();
#pragma unroll
        for (int kk = 0; kk < 32; ++kk) {
            float4 a4 = *(const float4*)(As + kk * 68 + ty * 4);
            float4 b4 = *(const float4*)(Bs + kk * 68 + tx * 4);
            float av[4] = {a4.x, a4.y, a4.z, a4.w};
            float bv[4] = {b4.x, b4.y, b4.z, b4.w};
#pragma unroll
            for (int i = 0; i < 4; ++i)
#pragma unroll
                for (int j = 0; j < 4; ++j) acc[i][j] += av[i] * bv[j];
        }
    }
#pragma unroll
    for (int i = 0; i < 4; ++i)
#pragma unroll
        for (int j = 0; j < 4; ++j)
            outw[(size_t)(rb + ty * 4 + i) * 256 + cb + tx * 4 + j] = acc[i][j];
}

// ---------------------------------------------------------------------------
// Convert fp32 (N x K row-major) -> bf16 MFMA-B swizzled layout:
// element (n,k) -> sw[((nt*(K/32)+kt)*64 + quad*16 + (n&15))*8 + (k&7)]
// where nt=n>>4, kt=k>>5, quad=(k&31)>>3. A wave's b_frag load is then one
// fully-coalesced 16B/lane read.
// ---------------------------------------------------------------------------
__global__ __launch_bounds__(256) void convert_swizzle(
    const float* __restrict__ src, __hip_bfloat16* __restrict__ dst, int N, int K)
{
    int idx = blockIdx.x * 256 + threadIdx.x;
    if (idx >= N * K) return;
    int n = idx / K, k = idx - n * K;
    int nt = n >> 4, kt = k >> 5, quad = (k & 31) >> 3, pos = k & 7;
    int lane = quad * 16 + (n & 15);
    dst[((size_t)(nt * (K >> 5) + kt) * 64 + lane) * 8 + pos] = (__hip_bfloat16)src[idx];
}

// ---------------------------------------------------------------------------
// MFMA GEMM: C = A @ W^T (+bias), bf16 out. A fp32 or bf16 row-major (M x K),
// W pre-swizzled bf16. Two row-regions (node/neighbor) pick A/W/bias by
// rowthresh. Tile 64(M) x 128(N), full-K A staged in LDS once per block.
//   slotmap=0: C row-major (N cols). slotmap=1: attention kv slot layout.
// ---------------------------------------------------------------------------
__global__ __launch_bounds__(256) void mfma_gemm(
    const void* __restrict__ A0, const void* __restrict__ A1, int rowthresh, int a_f32,
    const __hip_bfloat16* __restrict__ W0, const __hip_bfloat16* __restrict__ W1,
    const float* __restrict__ bias0, const float* __restrict__ bias1,
    __hip_bfloat16* __restrict__ Cout, int N, int K, int slotmap)
{
    __shared__ __align__(16) __hip_bfloat16 As[64 * 264];  // max K=256, pad +8
    const int tid = threadIdx.x, wave = tid >> 6, lane = tid & 63;
    const int quad = lane >> 4, lr = lane & 15;
    const int rb = blockIdx.x * 64, cb = blockIdx.y * 128;
    const bool reg0 = rb < rowthresh;
    const void* A = reg0 ? A0 : A1;
    const int arow0 = reg0 ? rb : rb - rowthresh;
    const __hip_bfloat16* W = reg0 ? W0 : W1;
    const float* bias = reg0 ? bias0 : bias1;
    const int nkt = K >> 5;
    const int stride = K + 8;
    const int csh = (K == 256) ? 5 : 4;   // log2(K/8)
    const int cmask = (K >> 3) - 1;

    // stage full A tile 64 x K into LDS (bf16)
    for (int f = tid; f < (K << 3); f += 256) {
        int row = f >> csh, cc = f & cmask;
        if (a_f32) {
            const float* Af = (const float*)A + (size_t)(arow0 + row) * K + cc * 8;
            float4 v0 = *(const float4*)Af;
            float4 v1 = *(const float4*)(Af + 4);
            __hip_bfloat16* d = As + row * stride + cc * 8;
            d[0] = (__hip_bfloat16)v0.x; d[1] = (__hip_bfloat16)v0.y;
            d[2] = (__hip_bfloat16)v0.z; d[3] = (__hip_bfloat16)v0.w;
            d[4] = (__hip_bfloat16)v1.x; d[5] = (__hip_bfloat16)v1.y;
            d[6] = (__hip_bfloat16)v1.z; d[7] = (__hip_bfloat16)v1.w;
        } else {
            const __hip_bfloat16* Ah = (const __hip_bfloat16*)A + (size_t)(arow0 + row) * K + cc * 8;
            *(uint4*)(void*)(As + row * stride + cc * 8) = *(const uint4*)(const void*)Ah;
        }
    }
    __syncthreads();

    f32x4 acc[8] = {};
    for (int kt = 0; kt < nkt; ++kt) {
        bf16x8 afr = *(const bf16x8*)(const void*)(As + (wave * 16 + lr) * stride + kt * 32 + quad * 8);
#pragma unroll
        for (int j = 0; j < 8; ++j) {
            int ntg = (cb >> 4) + j;
            bf16x8 bfr = *(const bf16x8*)(const void*)(W + ((size_t)(ntg * nkt + kt) * 64 + lane) * 8);
            acc[j] = __builtin_amdgcn_mfma_f32_16x16x32_bf16(afr, bfr, acc[j], 0, 0, 0);
        }
    }

#pragma unroll
    for (int j = 0; j < 8; ++j) {
        int col = cb + j * 16 + lr;
        float bv = bias ? bias[col] : 0.0f;
#pragma unroll
        for (int rg = 0; rg < 4; ++rg) {
            int row = rb + wave * 16 + quad * 4 + rg;
            size_t oidx;
            if (!slotmap) {
                oidx = (size_t)row * N + col;
            } else if (row < 4096) {
                int bb = row >> 6, s = row & 63;
                oidx = ((size_t)bb * 1088 + s) * 256 + col;
            } else {
                int rr = (row - 4096) >> 6, s = (row - 4096) & 63;
                int bb = rr >> 4, nn = rr & 15;
                oidx = ((size_t)bb * 1088 + (nn + 1) * 64 + s) * 256 + col;
            }
            Cout[oidx] = (__hip_bfloat16)(acc[j][rg] + bv);
        }
    }
}

// ---------------------------------------------------------------------------
// Persistent GRU scan. 68 blocks x 256 threads; block owns 16 rows of the
// 1088 (64 node + 1024 neighbor) sequences. h kept in LDS (fp32 master +
// bf16 A-fragment copy). Per step: gh = h @ Whh^T via MFMA with Whh streamed
// (pre-swizzled bf16) from L2; pointwise gates; seq outputs written bf16.
// ---------------------------------------------------------------------------
__global__ __launch_bounds__(256) void scan_kernel(
    const __hip_bfloat16* __restrict__ gi,        // 69632 x 768 (bih included)
    const __hip_bfloat16* __restrict__ Whh_n_sw,  // 48 ntiles x 8 kt x 64 x 8
    const __hip_bfloat16* __restrict__ Whh_g_sw,
    const float* __restrict__ bhh_node, const float* __restrict__ bhh_ngh,
    const float* __restrict__ node_hidden, const float* __restrict__ neighbors_hidden,
    __hip_bfloat16* __restrict__ node_out,  // 4096 x 256
    __hip_bfloat16* __restrict__ ngh_out,   // 65536 x 256
    float* __restrict__ out_node_hT, float* __restrict__ out_ngh_hT)
{
    __shared__ float h_f[16 * 260];
    __shared__ __align__(16) __hip_bfloat16 gh_b[16 * 776];
    __shared__ __align__(16) __hip_bfloat16 h_frag[8 * 64 * 8];  // [kt][lane][8]
    __shared__ float bhh_l[768];
    const int tid = threadIdx.x;
    const int wave = tid >> 6, lane = tid & 63;
    const int quad = lane >> 4, lr = lane & 15;
    const int row0 = blockIdx.x * 16;
    const bool isnode = (row0 < 64);
    const __hip_bfloat16* Wsw = isnode ? Whh_n_sw : Whh_g_sw;
    const float* bhh = isnode ? bhh_node : bhh_ngh;
    const int pr = tid & 15;            // pointwise row
    const int pc0 = (tid >> 4) * 16;    // pointwise col block

    // init: bhh to LDS, h0 to LDS (fp32 + frag bf16)
    for (int f = tid; f < 768; f += 256) bhh_l[f] = bhh[f];
    {
        const float* src = isnode ? (node_hidden + (size_t)row0 * 256)
                                  : (neighbors_hidden + (size_t)(row0 - 64) * 256);
        for (int jj = 0; jj < 16; ++jj) {
            int j = pc0 + jj;
            float v = src[(size_t)pr * 256 + j];
            h_f[pr * 260 + j] = v;
            h_frag[((j >> 5) * 64 + ((j & 31) >> 3) * 16 + pr) * 8 + (j & 7)] = (__hip_bfloat16)v;
        }
    }
    __syncthreads();

    for (int t = 0; t < 64; ++t) {
        // ---- MFMA phase: gh[16x768] = h @ Whh^T; wave handles n-tiles wave*12..+11
        bf16x8 afr[8];
#pragma unroll
        for (int kt = 0; kt < 8; ++kt)
            afr[kt] = *(const bf16x8*)(const void*)(h_frag + (kt * 64 + lane) * 8);
        for (int nt = 0; nt < 12; ++nt) {
            int ntg = wave * 12 + nt;
            f32x4 acc = {0.f, 0.f, 0.f, 0.f};
#pragma unroll
            for (int kt = 0; kt < 8; ++kt) {
                bf16x8 bfr = *(const bf16x8*)(const void*)(Wsw + ((size_t)(ntg * 8 + kt) * 64 + lane) * 8);
                acc = __builtin_amdgcn_mfma_f32_16x16x32_bf16(afr[kt], bfr, acc, 0, 0, 0);
            }
            int col = ntg * 16 + lr;
#pragma unroll
            for (int rg = 0; rg < 4; ++rg)
                gh_b[(quad * 4 + rg) * 776 + col] = (__hip_bfloat16)acc[rg];
        }
        __syncthreads();

        // ---- pointwise gates for this block's 16 rows
        {
            int grow = row0 + pr;
            size_t girow = isnode ? ((size_t)grow * 64 + t)
                                  : (4096 + (size_t)(grow - 64) * 64 + t);
            const __hip_bfloat16* g = gi + girow * 768;
            short gr[16], gz[16], gn[16];
            *(bf16x8*)(void*)gr       = *(const bf16x8*)(const void*)(g + pc0);
            *(bf16x8*)(void*)(gr + 8) = *(const bf16x8*)(const void*)(g + pc0 + 8);
            *(bf16x8*)(void*)gz       = *(const bf16x8*)(const void*)(g + 256 + pc0);
            *(bf16x8*)(void*)(gz + 8) = *(const bf16x8*)(const void*)(g + 256 + pc0 + 8);
            *(bf16x8*)(void*)gn       = *(const bf16x8*)(const void*)(g + 512 + pc0);
            *(bf16x8*)(void*)(gn + 8) = *(const bf16x8*)(const void*)(g + 512 + pc0 + 8);
            __hip_bfloat16 tmp[16];
#pragma unroll
            for (int jj = 0; jj < 16; ++jj) {
                int j = pc0 + jj;
                float ghr = bf2f(*(unsigned short*)&gh_b[pr * 776 + j])       + bhh_l[j];
                float ghz = bf2f(*(unsigned short*)&gh_b[pr * 776 + 256 + j]) + bhh_l[256 + j];
                float ghn = bf2f(*(unsigned short*)&gh_b[pr * 776 + 512 + j]) + bhh_l[512 + j];
                float rg = sigmoidf_(bf2f((unsigned short)gr[jj]) + ghr);
                float zg = sigmoidf_(bf2f((unsigned short)gz[jj]) + ghz);
                float ng = tanhf_(bf2f((unsigned short)gn[jj]) + rg * ghn);
                float hp = h_f[pr * 260 + j];
                float hn = (1.0f - zg) * ng + zg * hp;
                h_f[pr * 260 + j] = hn;
                __hip_bfloat16 hb = (__hip_bfloat16)hn;
                h_frag[((j >> 5) * 64 + ((j & 31) >> 3) * 16 + pr) * 8 + (j & 7)] = hb;
                tmp[jj] = hb;
            }
            __hip_bfloat16* orow = isnode
                ? (node_out + ((size_t)grow * 64 + t) * 256)
                : (ngh_out + ((size_t)(grow - 64) * 64 + t) * 256);
            *(uint4*)(void*)(orow + pc0)     = *(const uint4*)(const void*)tmp;
            *(uint4*)(void*)(orow + pc0 + 8) = *(const uint4*)(const void*)(tmp + 8);
        }
        __syncthreads();
    }

    // final hidden states (fp32)
    {
        float* dst = isnode ? (out_node_hT + (size_t)row0 * 256)
                            : (out_ngh_hT + (size_t)(row0 - 64) * 256);
        for (int jj = 0; jj < 16; ++jj)
            dst[(size_t)pr * 256 + pc0 + jj] = h_f[pr * 260 + pc0 + jj];
    }
}

// ---------------------------------------------------------------------------
// Fused attention per (b,m): S = Qb@K^T (+bbil, causal) -> softmax (A to
// d_out) -> ctx = A@V -> projection dot(ctx, Wprj) -> atomicAdd out[b,t].
// ---------------------------------------------------------------------------
__global__ __launch_bounds__(256) void attn_kernel(
    const __hip_bfloat16* __restrict__ Qb, const __hip_bfloat16* __restrict__ Kb,
    const __hip_bfloat16* __restrict__ Vb, const float* __restrict__ bbil,
    const float* __restrict__ Wprj, const float* __restrict__ bprj,
    float* __restrict__ A_out, float* __restrict__ out)
{
    __shared__ __align__(16) float Sbuf[64 * 68];
    __shared__ __align__(16) float Stage[64 * 68];
    __shared__ float rowmax[64], rowrcp[64];
    __shared__ float red[1024];
    const int tid = threadIdx.x;
    const int tx = tid & 15, ty = tid >> 4;
    const int bm = blockIdx.x;
    const int b = bm / 17, m = bm % 17;
    const __hip_bfloat16* Qrow = Qb + (size_t)b * 64 * 256;
    const __hip_bfloat16* Krow = Kb + ((size_t)b * 1088 + m * 64) * 256;
    const __hip_bfloat16* Vrow = Vb + ((size_t)b * 1088 + m * 64) * 256;

    float acc[4][4] = {};
    for (int k0 = 0; k0 < 256; k0 += 32) {
        __syncthreads();
        for (int f = tid; f < 2048; f += 256) {
            int r = f >> 5, kk = f & 31;
            Stage[kk * 68 + r] = (float)Qrow[(size_t)r * 256 + (k0 + kk)];
        }
        for (int f = tid; f < 2048; f += 256) {
            int s = f >> 5, kk = f & 31;
            Stage[2176 + kk * 68 + s] = (float)Krow[(size_t)s * 256 + (k0 + kk)];
        }
        __syncthreads();
#pragma unroll
        for (int kk = 0; kk < 32; ++kk) {
            float4 a4 = *(const float4*)(Stage + kk * 68 + ty * 4);
            float4 b4 = *(const float4*)(Stage + 2176 + kk * 68 + tx * 4);
            float av[4] = {a4.x, a4.y, a4.z, a4.w};
            float bv[4] = {b4.x, b4.y, b4.z, b4.w};
#pragma unroll
            for (int i = 0; i < 4; ++i)
#pragma unroll
                for (int j = 0; j < 4; ++j) acc[i][j] += av[i] * bv[j];
        }
    }
    __syncthreads();
#pragma unroll
    for (int i = 0; i < 4; ++i)
#pragma unroll
        for (int j = 0; j < 4; ++j) {
            int t = ty * 4 + i, s = tx * 4 + j;
            Sbuf[t * 68 + s] = (s <= t) ? (acc[i][j] + bbil[s]) : NEGV;
        }
    __syncthreads();
    if (tid < 64) {
        float mx = -3.0e38f;
        for (int s = 0; s < 64; ++s) mx = fmaxf(mx, Sbuf[tid * 68 + s]);
        float sum = 0.0f;
        for (int s = 0; s < 64; ++s) sum += __expf(Sbuf[tid * 68 + s] - mx);
        rowmax[tid] = mx;
        rowrcp[tid] = 1.0f / sum;
    }
    __syncthreads();
    for (int idx = tid; idx < 4096; idx += 256) {
        int t = idx >> 6, s = idx & 63;
        float e = __expf(Sbuf[t * 68 + s] - rowmax[t]) * rowrcp[t];
        A_out[(size_t)bm * 4096 + idx] = e;
        Sbuf[t * 68 + s] = e;
    }
    float partial[4] = {0.f, 0.f, 0.f, 0.f};
    for (int hq = 0; hq < 4; ++hq) {
        __syncthreads();
        for (int f = tid; f < 4096; f += 256) {
            int s = f >> 6, c = f & 63;
            Stage[s * 68 + c] = (float)Vrow[(size_t)s * 256 + hq * 64 + c];
        }
        __syncthreads();
        float cacc[4][4] = {};
#pragma unroll 4
        for (int kk = 0; kk < 64; ++kk) {
            float a0 = Sbuf[(ty * 4 + 0) * 68 + kk];
            float a1 = Sbuf[(ty * 4 + 1) * 68 + kk];
            float a2 = Sbuf[(ty * 4 + 2) * 68 + kk];
            float a3 = Sbuf[(ty * 4 + 3) * 68 + kk];
            float4 b4 = *(const float4*)(Stage + kk * 68 + tx * 4);
            float bv[4] = {b4.x, b4.y, b4.z, b4.w};
#pragma unroll
            for (int j = 0; j < 4; ++j) {
                cacc[0][j] += a0 * bv[j];
                cacc[1][j] += a1 * bv[j];
                cacc[2][j] += a2 * bv[j];
                cacc[3][j] += a3 * bv[j];
            }
        }
#pragma unroll
        for (int i = 0; i < 4; ++i)
#pragma unroll
            for (int j = 0; j < 4; ++j)
                partial[i] += cacc[i][j] * Wprj[hq * 64 + tx * 4 + j];
    }
#pragma unroll
    for (int i = 0; i < 4; ++i) red[(ty * 4 + i) * 16 + tx] = partial[i];
    __syncthreads();
    if (tid < 64) {
        float s = 0.0f;
#pragma unroll
        for (int q = 0; q < 16; ++q) s += red[tid * 16 + q];
        if (m == 0) s += 17.0f * bprj[0];
        atomicAdd(out + b * 64 + tid, s);
    }
}

// ---------------------------------------------------------------------------
extern "C" void kernel_launch(void* const* d_in, const int* in_sizes, int n_in,
                              void* d_out, int out_size, void* d_ws, size_t ws_size,
                              hipStream_t stream)
{
    const float* node_input       = (const float*)d_in[0];
    const float* node_hidden      = (const float*)d_in[1];
    const float* neighbors_input  = (const float*)d_in[2];
    const float* neighbors_hidden = (const float*)d_in[3];
    const float* Wih_node = (const float*)d_in[5];
    const float* Whh_node = (const float*)d_in[6];
    const float* bih_node = (const float*)d_in[7];
    const float* bhh_node = (const float*)d_in[8];
    const float* Wih_ngh  = (const float*)d_in[9];
    const float* Whh_ngh  = (const float*)d_in[10];
    const float* bih_ngh  = (const float*)d_in[11];
    const float* bhh_ngh  = (const float*)d_in[12];
    const float* Wq   = (const float*)d_in[13];
    const float* Wk   = (const float*)d_in[14];
    const float* Wv   = (const float*)d_in[15];
    const float* Wbil = (const float*)d_in[16];
    const float* bbil = (const float*)d_in[17];
    const float* Wprj = (const float*)d_in[18];
    const float* bprj = (const float*)d_in[19];

    float* out         = (float*)d_out;          // (B,T)     4096
    float* out_node_hT = out + 4096;             // (1,B,H)   16384
    float* out_ngh_hT  = out + 20480;            // (1,B*N,H) 262144
    float* out_A       = out + 282624;           // (B,17,T,T)

    // ---- workspace layout (bytes) ----
    char* w = (char*)d_ws;
    float*          wqb_f    = (float*)(w);                  // 262144 B
    __hip_bfloat16* Wih_n_sw = (__hip_bfloat16*)(w + 262144);    // 196608 B
    __hip_bfloat16* Wih_g_sw = (__hip_bfloat16*)(w + 458752);    // 196608
    __hip_bfloat16* Whh_n_sw = (__hip_bfloat16*)(w + 655360);    // 393216
    __hip_bfloat16* Whh_g_sw = (__hip_bfloat16*)(w + 1048576);   // 393216
    __hip_bfloat16* Wk_sw    = (__hip_bfloat16*)(w + 1441792);   // 131072
    __hip_bfloat16* Wv_sw    = (__hip_bfloat16*)(w + 1572864);   // 131072
    __hip_bfloat16* wqb_sw   = (__hip_bfloat16*)(w + 1703936);   // 131072
    __hip_bfloat16* node_out_b = (__hip_bfloat16*)(w + 1835008); // 2097152
    __hip_bfloat16* ngh_out_b  = (__hip_bfloat16*)(w + 3932160); // 33554432
    __hip_bfloat16* qb_b       = (__hip_bfloat16*)(w + 37486592);// 2097152
    __hip_bfloat16* gi         = (__hip_bfloat16*)(w + 39583744);// 106954752
    __hip_bfloat16* kbuf = gi;                      // reuse gi region after scan
    __hip_bfloat16* vbuf = kbuf + 17825792;         // 69632*256 each
    // end: 39583744 + 106954752 = 146538496 B (< proven-available 155 MB)

    hipMemsetAsync(d_out, 0, 4096 * sizeof(float), stream);

    // wqb_t = Wbil^T-fold: wqb_t[h'][d] = sum_k Wbil[k][h'] Wq[k][d]
    wqb_gemm<<<dim3(4, 4), 256, 0, stream>>>(Wbil, Wq, wqb_f);

    // weight conversions to swizzled bf16
    convert_swizzle<<<384, 256, 0, stream>>>(Wih_node, Wih_n_sw, 768, 128);
    convert_swizzle<<<384, 256, 0, stream>>>(Wih_ngh,  Wih_g_sw, 768, 128);
    convert_swizzle<<<768, 256, 0, stream>>>(Whh_node, Whh_n_sw, 768, 256);
    convert_swizzle<<<768, 256, 0, stream>>>(Whh_ngh,  Whh_g_sw, 768, 256);
    convert_swizzle<<<256, 256, 0, stream>>>(Wk,    Wk_sw,  256, 256);
    convert_swizzle<<<256, 256, 0, stream>>>(Wv,    Wv_sw,  256, 256);
    convert_swizzle<<<256, 256, 0, stream>>>(wqb_f, wqb_sw, 256, 256);

    // gi = x @ Wih^T + bih (both GRUs), bf16, rows: node 0..4095, ngh 4096..
    mfma_gemm<<<dim3(1088, 6), 256, 0, stream>>>(
        node_input, neighbors_input, 4096, 1,
        Wih_n_sw, Wih_g_sw, bih_node, bih_ngh,
        gi, 768, 128, 0);

    // persistent GRU scan
    scan_kernel<<<68, 256, 0, stream>>>(gi, Whh_n_sw, Whh_g_sw,
        bhh_node, bhh_ngh, node_hidden, neighbors_hidden,
        node_out_b, ngh_out_b, out_node_hT, out_ngh_hT);

    // K, V (slot-mapped), Qb
    mfma_gemm<<<dim3(1088, 2), 256, 0, stream>>>(
        node_out_b, ngh_out_b, 4096, 0, Wk_sw, Wk_sw, nullptr, nullptr,
        kbuf, 256, 256, 1);
    mfma_gemm<<<dim3(1088, 2), 256, 0, stream>>>(
        node_out_b, ngh_out_b, 4096, 0, Wv_sw, Wv_sw, nullptr, nullptr,
        vbuf, 256, 256, 1);
    mfma_gemm<<<dim3(64, 2), 256, 0, stream>>>(
        node_out_b, node_out_b, 1 << 30, 0, wqb_sw, wqb_sw, nullptr, nullptr,
        qb_b, 256, 256, 0);

    // fused attention
    attn_kernel<<<1088, 256, 0, stream>>>(qb_b, kbuf, vbuf, bbil, Wprj, bprj,
                                          out_A, out);
}

// Round 3
// 592.834 us; speedup vs baseline: 4.4034x; 1.2738x over previous
//
#include <hip/hip_runtime.h>
#include <hip/hip_bf16.h>

#define NEGV -1e30f
typedef __attribute__((ext_vector_type(8))) short bf16x8;
typedef __attribute__((ext_vector_type(4))) float f32x4;

__device__ __forceinline__ float sigmoidf_(float x) { return 1.0f / (1.0f + __expf(-x)); }
__device__ __forceinline__ float tanhf_(float x) {
    float ax = fabsf(x);
    float e = __expf(-2.0f * ax);
    float t = (1.0f - e) / (1.0f + e);
    return copysignf(t, x);
}
__device__ __forceinline__ float bf2f(unsigned short u) {
    union { float f; unsigned int i; } x; x.i = ((unsigned int)u) << 16; return x.f;
}

// ---------------------------------------------------------------------------
// Small fp32 GEMM for wqb_t[h'][d] = sum_k Wbil[k][h'] * Wq[k][d]  (256x256)
// ---------------------------------------------------------------------------
__global__ __launch_bounds__(256) void wqb_gemm(const float* __restrict__ Wbil_,
    const float* __restrict__ Wq_, float* __restrict__ outw)
{
    __shared__ __align__(16) float As[32 * 68];
    __shared__ __align__(16) float Bs[32 * 68];
    const int tid = threadIdx.x, tx = tid & 15, ty = tid >> 4;
    const int rb = blockIdx.x * 64, cb = blockIdx.y * 64;
    float acc[4][4] = {};
    for (int k0 = 0; k0 < 256; k0 += 32) {
        __syncthreads();
        for (int f = tid; f < 2048; f += 256) {
            int kk = f >> 6, r = f & 63;
            As[kk * 68 + r] = Wbil_[(size_t)(k0 + kk) * 256 + rb + r];
        }
        for (int f = tid; f < 2048; f += 256) {
            int kk = f >> 6, c = f & 63;
            Bs[kk * 68 + c] = Wq_[(size_t)(k0 + kk) * 256 + cb + c];
        }
        __syncthreads();
#pragma unroll
        for (int kk = 0; kk < 32; ++kk) {
            float4 a4 = *(const float4*)(As + kk * 68 + ty * 4);
            float4 b4 = *(const float4*)(Bs + kk * 68 + tx * 4);
            float av[4] = {a4.x, a4.y, a4.z, a4.w};
            float bv[4] = {b4.x, b4.y, b4.z, b4.w};
#pragma unroll
            for (int i = 0; i < 4; ++i)
#pragma unroll
                for (int j = 0; j < 4; ++j) acc[i][j] += av[i] * bv[j];
        }
    }
#pragma unroll
    for (int i = 0; i < 4; ++i)
#pragma unroll
        for (int j = 0; j < 4; ++j)
            outw[(size_t)(rb + ty * 4 + i) * 256 + cb + tx * 4 + j] = acc[i][j];
}

// ---------------------------------------------------------------------------
// fp32 (N x K) -> bf16 MFMA-B swizzled: (n,k) -> [((nt*(K/32)+kt)*64+lane)*8+pos]
// ---------------------------------------------------------------------------
__global__ __launch_bounds__(256) void convert_swizzle(
    const float* __restrict__ src, __hip_bfloat16* __restrict__ dst, int N, int K)
{
    int idx = blockIdx.x * 256 + threadIdx.x;
    if (idx >= N * K) return;
    int n = idx / K, k = idx - n * K;
    int nt = n >> 4, kt = k >> 5, quad = (k & 31) >> 3, pos = k & 7;
    int lane = quad * 16 + (n & 15);
    dst[((size_t)(nt * (K >> 5) + kt) * 64 + lane) * 8 + pos] = (__hip_bfloat16)src[idx];
}

// ---------------------------------------------------------------------------
// MFMA GEMM: C = A @ W^T (+bias). Tile 64(M) x 128(N).
//   slotmap 0: row-major. 1: kv slot layout [b][slot*64+s][256].
//   slotmap 2: TRANSPOSED kv layout [(b*17+m)*256 + col]*64 + s  (for V^T).
// ---------------------------------------------------------------------------
__global__ __launch_bounds__(256) void mfma_gemm(
    const void* __restrict__ A0, const void* __restrict__ A1, int rowthresh, int a_f32,
    const __hip_bfloat16* __restrict__ W0, const __hip_bfloat16* __restrict__ W1,
    const float* __restrict__ bias0, const float* __restrict__ bias1,
    __hip_bfloat16* __restrict__ Cout, int N, int K, int slotmap)
{
    __shared__ __align__(16) __hip_bfloat16 As[64 * 264];
    const int tid = threadIdx.x, wave = tid >> 6, lane = tid & 63;
    const int quad = lane >> 4, lr = lane & 15;
    const int rb = blockIdx.x * 64, cb = blockIdx.y * 128;
    const bool reg0 = rb < rowthresh;
    const void* A = reg0 ? A0 : A1;
    const int arow0 = reg0 ? rb : rb - rowthresh;
    const __hip_bfloat16* W = reg0 ? W0 : W1;
    const float* bias = reg0 ? bias0 : bias1;
    const int nkt = K >> 5;
    const int stride = K + 8;
    const int csh = (K == 256) ? 5 : 4;
    const int cmask = (K >> 3) - 1;

    for (int f = tid; f < (K << 3); f += 256) {
        int row = f >> csh, cc = f & cmask;
        if (a_f32) {
            const float* Af = (const float*)A + (size_t)(arow0 + row) * K + cc * 8;
            float4 v0 = *(const float4*)Af;
            float4 v1 = *(const float4*)(Af + 4);
            __hip_bfloat16* d = As + row * stride + cc * 8;
            d[0] = (__hip_bfloat16)v0.x; d[1] = (__hip_bfloat16)v0.y;
            d[2] = (__hip_bfloat16)v0.z; d[3] = (__hip_bfloat16)v0.w;
            d[4] = (__hip_bfloat16)v1.x; d[5] = (__hip_bfloat16)v1.y;
            d[6] = (__hip_bfloat16)v1.z; d[7] = (__hip_bfloat16)v1.w;
        } else {
            const __hip_bfloat16* Ah = (const __hip_bfloat16*)A + (size_t)(arow0 + row) * K + cc * 8;
            *(uint4*)(void*)(As + row * stride + cc * 8) = *(const uint4*)(const void*)Ah;
        }
    }
    __syncthreads();

    f32x4 acc[8] = {};
    for (int kt = 0; kt < nkt; ++kt) {
        bf16x8 afr = *(const bf16x8*)(const void*)(As + (wave * 16 + lr) * stride + kt * 32 + quad * 8);
#pragma unroll
        for (int j = 0; j < 8; ++j) {
            int ntg = (cb >> 4) + j;
            bf16x8 bfr = *(const bf16x8*)(const void*)(W + ((size_t)(ntg * nkt + kt) * 64 + lane) * 8);
            acc[j] = __builtin_amdgcn_mfma_f32_16x16x32_bf16(afr, bfr, acc[j], 0, 0, 0);
        }
    }

#pragma unroll
    for (int j = 0; j < 8; ++j) {
        int col = cb + j * 16 + lr;
        float bv = bias ? bias[col] : 0.0f;
        if (slotmap == 2) {
            int row = rb + wave * 16 + quad * 4;
            int b_, m_, s_;
            if (row < 4096) { b_ = row >> 6; m_ = 0; s_ = row & 63; }
            else {
                int rr = (row - 4096) >> 6;
                b_ = rr >> 4; m_ = (rr & 15) + 1; s_ = (row - 4096) & 63;
            }
            __hip_bfloat16 t4[4];
#pragma unroll
            for (int rg = 0; rg < 4; ++rg) t4[rg] = (__hip_bfloat16)(acc[j][rg] + bv);
            *(uint2*)(void*)(Cout + ((size_t)(b_ * 17 + m_) * 256 + col) * 64 + s_) =
                *(const uint2*)(const void*)t4;
        } else {
#pragma unroll
            for (int rg = 0; rg < 4; ++rg) {
                int row = rb + wave * 16 + quad * 4 + rg;
                size_t oidx;
                if (!slotmap) {
                    oidx = (size_t)row * N + col;
                } else if (row < 4096) {
                    int bb = row >> 6, s = row & 63;
                    oidx = ((size_t)bb * 1088 + s) * 256 + col;
                } else {
                    int rr = (row - 4096) >> 6, s = (row - 4096) & 63;
                    int bb = rr >> 4, nn = rr & 15;
                    oidx = ((size_t)bb * 1088 + (nn + 1) * 64 + s) * 256 + col;
                }
                Cout[oidx] = (__hip_bfloat16)(acc[j][rg] + bv);
            }
        }
    }
}

// ---------------------------------------------------------------------------
// Weight-stationary persistent GRU scan. 68 blocks x 512 threads (8 waves).
// Whh (768x256 bf16, pre-swizzled) lives in registers: wave w owns n-tiles
// 6w..6w+5 => 48 bf16x8 fragments/lane (192 VGPRs). MFMA phase has zero
// global loads; kt-outer/nt-inner gives 6 independent acc chains.
// gi double-buffered one step ahead (HBM latency off critical path).
// ---------------------------------------------------------------------------
struct GiBuf { bf16x8 r, z, n; };

__global__ __launch_bounds__(512) void scan_kernel(
    const __hip_bfloat16* __restrict__ gi,
    const __hip_bfloat16* __restrict__ Whh_n_sw,
    const __hip_bfloat16* __restrict__ Whh_g_sw,
    const float* __restrict__ bhh_node, const float* __restrict__ bhh_ngh,
    const float* __restrict__ node_hidden, const float* __restrict__ neighbors_hidden,
    __hip_bfloat16* __restrict__ node_out, __hip_bfloat16* __restrict__ ngh_out,
    float* __restrict__ out_node_hT, float* __restrict__ out_ngh_hT)
{
    __shared__ float h_f[16 * 260];
    __shared__ __align__(16) __hip_bfloat16 gh_b[16 * 776];
    __shared__ __align__(16) __hip_bfloat16 h_frag[8 * 64 * 8];
    __shared__ float bhh_l[768];
    const int tid = threadIdx.x;
    const int wave = tid >> 6, lane = tid & 63;
    const int quad = lane >> 4, lr = lane & 15;
    const int row0 = blockIdx.x * 16;
    const bool isnode = (row0 < 64);
    const __hip_bfloat16* Wsw = isnode ? Whh_n_sw : Whh_g_sw;
    const float* bhh = isnode ? bhh_node : bhh_ngh;
    const int pr = tid & 15;
    const int pc0 = (tid >> 4) * 8;   // 0..248
    const int grow = row0 + pr;
    const size_t gibase = isnode ? ((size_t)grow * 64) : (4096 + (size_t)(grow - 64) * 64);
    const int fragoff = ((pc0 >> 5) * 64 + ((pc0 & 31) >> 3) * 16 + pr) * 8;

    // stationary weights -> registers (48 x 16B per lane)
    bf16x8 wreg[48];
#pragma unroll
    for (int nt = 0; nt < 6; ++nt)
#pragma unroll
        for (int kt = 0; kt < 8; ++kt)
            wreg[nt * 8 + kt] = *(const bf16x8*)(const void*)(
                Wsw + ((size_t)((wave * 6 + nt) * 8 + kt) * 64 + lane) * 8);

    for (int f = tid; f < 768; f += 512) bhh_l[f] = bhh[f];
    {
        const float* src = isnode ? (node_hidden + (size_t)row0 * 256)
                                  : (neighbors_hidden + (size_t)(row0 - 64) * 256);
        float4 v0 = *(const float4*)(src + (size_t)pr * 256 + pc0);
        float4 v1 = *(const float4*)(src + (size_t)pr * 256 + pc0 + 4);
        float vv[8] = {v0.x, v0.y, v0.z, v0.w, v1.x, v1.y, v1.z, v1.w};
        __hip_bfloat16 hb[8];
#pragma unroll
        for (int jj = 0; jj < 8; ++jj) {
            h_f[pr * 260 + pc0 + jj] = vv[jj];
            hb[jj] = (__hip_bfloat16)vv[jj];
        }
        *(uint4*)(void*)(h_frag + fragoff) = *(const uint4*)(const void*)hb;
    }
    __syncthreads();

    auto gi_load = [&](int t) {
        GiBuf g;
        const __hip_bfloat16* gp = gi + (gibase + t) * 768;
        g.r = *(const bf16x8*)(const void*)(gp + pc0);
        g.z = *(const bf16x8*)(const void*)(gp + 256 + pc0);
        g.n = *(const bf16x8*)(const void*)(gp + 512 + pc0);
        return g;
    };

    auto step = [&](int t, GiBuf& use, GiBuf& fill) {
        // prefetch next step's gi (consumed next step; latency hidden)
        fill = gi_load((t < 63) ? t + 1 : 63);
        // ---- MFMA: gh = h @ Whh^T, zero global loads
        f32x4 acc[6] = {{0.f,0.f,0.f,0.f},{0.f,0.f,0.f,0.f},{0.f,0.f,0.f,0.f},
                        {0.f,0.f,0.f,0.f},{0.f,0.f,0.f,0.f},{0.f,0.f,0.f,0.f}};
#pragma unroll
        for (int kt = 0; kt < 8; ++kt) {
            bf16x8 afr = *(const bf16x8*)(const void*)(h_frag + (kt * 64 + lane) * 8);
#pragma unroll
            for (int nt = 0; nt < 6; ++nt)
                acc[nt] = __builtin_amdgcn_mfma_f32_16x16x32_bf16(afr, wreg[nt * 8 + kt], acc[nt], 0, 0, 0);
        }
#pragma unroll
        for (int nt = 0; nt < 6; ++nt) {
            int col = (wave * 6 + nt) * 16 + lr;
#pragma unroll
            for (int rg = 0; rg < 4; ++rg)
                gh_b[(quad * 4 + rg) * 776 + col] = (__hip_bfloat16)acc[nt][rg];
        }
        __syncthreads();
        // ---- pointwise gates (8 elems/thread)
        {
            bf16x8 ghr8 = *(const bf16x8*)(const void*)(gh_b + pr * 776 + pc0);
            bf16x8 ghz8 = *(const bf16x8*)(const void*)(gh_b + pr * 776 + 256 + pc0);
            bf16x8 ghn8 = *(const bf16x8*)(const void*)(gh_b + pr * 776 + 512 + pc0);
            __hip_bfloat16 hb[8];
#pragma unroll
            for (int jj = 0; jj < 8; ++jj) {
                int j = pc0 + jj;
                float ghr = bf2f((unsigned short)ghr8[jj]) + bhh_l[j];
                float ghz = bf2f((unsigned short)ghz8[jj]) + bhh_l[256 + j];
                float ghn = bf2f((unsigned short)ghn8[jj]) + bhh_l[512 + j];
                float rg_ = sigmoidf_(bf2f((unsigned short)use.r[jj]) + ghr);
                float zg  = sigmoidf_(bf2f((unsigned short)use.z[jj]) + ghz);
                float ng  = tanhf_(bf2f((unsigned short)use.n[jj]) + rg_ * ghn);
                float hp = h_f[pr * 260 + j];
                float hn = (1.0f - zg) * ng + zg * hp;
                h_f[pr * 260 + j] = hn;
                hb[jj] = (__hip_bfloat16)hn;
            }
            *(uint4*)(void*)(h_frag + fragoff) = *(const uint4*)(const void*)hb;
            __hip_bfloat16* orow = isnode
                ? (node_out + ((size_t)grow * 64 + t) * 256)
                : (ngh_out + ((size_t)(grow - 64) * 64 + t) * 256);
            *(uint4*)(void*)(orow + pc0) = *(const uint4*)(const void*)hb;
        }
        __syncthreads();
    };

    GiBuf bufA = gi_load(0), bufB;
    for (int t = 0; t < 64; t += 2) {
        step(t, bufA, bufB);
        step(t + 1, bufB, bufA);
    }

    {
        float* dst = isnode ? (out_node_hT + (size_t)row0 * 256)
                            : (out_ngh_hT + (size_t)(row0 - 64) * 256);
        float v[8];
#pragma unroll
        for (int jj = 0; jj < 8; ++jj) v[jj] = h_f[pr * 260 + pc0 + jj];
        *(float4*)(dst + (size_t)pr * 256 + pc0)     = *(const float4*)v;
        *(float4*)(dst + (size_t)pr * 256 + pc0 + 4) = *(const float4*)(v + 4);
    }
}

// ---------------------------------------------------------------------------
// Fused attention per (b,m), MFMA-based. Q/K fragments straight from global
// (row-major == native A/B layout); V pre-transposed (Vt). S -> softmax (A to
// d_out, P bf16 to LDS) -> ctx=P@V via MFMA -> proj dot Wprj -> atomicAdd.
// ---------------------------------------------------------------------------
__global__ __launch_bounds__(256) void attn_kernel(
    const __hip_bfloat16* __restrict__ Qb, const __hip_bfloat16* __restrict__ Kb,
    const __hip_bfloat16* __restrict__ Vt, const float* __restrict__ bbil,
    const float* __restrict__ Wprj, const float* __restrict__ bprj,
    float* __restrict__ A_out, float* __restrict__ out)
{
    __shared__ __align__(16) float Sbuf[64 * 68];
    __shared__ __align__(16) __hip_bfloat16 Pb[64 * 72];
    __shared__ float rowmax[64], rowrcp[64];
    __shared__ float red[64 * 16];
    const int tid = threadIdx.x;
    const int wave = tid >> 6, lane = tid & 63;
    const int quad = lane >> 4, lr = lane & 15;
    const int bm = blockIdx.x, b = bm / 17, m = bm % 17;
    const __hip_bfloat16* Qrow = Qb + (size_t)b * 64 * 256;
    const __hip_bfloat16* Krow = Kb + ((size_t)b * 1088 + m * 64) * 256;
    const __hip_bfloat16* Vtrow = Vt + (size_t)(b * 17 + m) * 256 * 64;

    // ---- S = Q @ K^T
    f32x4 sacc[4] = {{0.f,0.f,0.f,0.f},{0.f,0.f,0.f,0.f},{0.f,0.f,0.f,0.f},{0.f,0.f,0.f,0.f}};
#pragma unroll
    for (int kt = 0; kt < 8; ++kt) {
        bf16x8 afr = *(const bf16x8*)(const void*)(Qrow + (size_t)(wave * 16 + lr) * 256 + kt * 32 + quad * 8);
#pragma unroll
        for (int c = 0; c < 4; ++c) {
            bf16x8 bfr = *(const bf16x8*)(const void*)(Krow + (size_t)(c * 16 + lr) * 256 + kt * 32 + quad * 8);
            sacc[c] = __builtin_amdgcn_mfma_f32_16x16x32_bf16(afr, bfr, sacc[c], 0, 0, 0);
        }
    }
#pragma unroll
    for (int c = 0; c < 4; ++c)
#pragma unroll
        for (int rg = 0; rg < 4; ++rg) {
            int t_ = wave * 16 + quad * 4 + rg, s_ = c * 16 + lr;
            Sbuf[t_ * 68 + s_] = (s_ <= t_) ? (sacc[c][rg] + bbil[s_]) : NEGV;
        }
    __syncthreads();
    if (tid < 64) {
        float mx = -3.0e38f;
        for (int s = 0; s < 64; ++s) mx = fmaxf(mx, Sbuf[tid * 68 + s]);
        float sum = 0.0f;
        for (int s = 0; s < 64; ++s) sum += __expf(Sbuf[tid * 68 + s] - mx);
        rowmax[tid] = mx;
        rowrcp[tid] = 1.0f / sum;
    }
    __syncthreads();
    for (int idx = tid; idx < 4096; idx += 256) {
        int t_ = idx >> 6, s_ = idx & 63;
        float e = __expf(Sbuf[t_ * 68 + s_] - rowmax[t_]) * rowrcp[t_];
        A_out[(size_t)bm * 4096 + idx] = e;
        Pb[t_ * 72 + s_] = (__hip_bfloat16)e;
    }
    __syncthreads();

    // ---- ctx = P @ V (V^T fragments contiguous), fused projection
    bf16x8 pfr[2];
#pragma unroll
    for (int k2 = 0; k2 < 2; ++k2)
        pfr[k2] = *(const bf16x8*)(const void*)(Pb + (wave * 16 + lr) * 72 + k2 * 32 + quad * 8);
    float part[4] = {0.f, 0.f, 0.f, 0.f};
#pragma unroll
    for (int nt = 0; nt < 16; ++nt) {
        f32x4 cacc = {0.f, 0.f, 0.f, 0.f};
#pragma unroll
        for (int k2 = 0; k2 < 2; ++k2) {
            bf16x8 bfr = *(const bf16x8*)(const void*)(Vtrow + (size_t)(nt * 16 + lr) * 64 + k2 * 32 + quad * 8);
            cacc = __builtin_amdgcn_mfma_f32_16x16x32_bf16(pfr[k2], bfr, cacc, 0, 0, 0);
        }
        float wp = Wprj[nt * 16 + lr];
#pragma unroll
        for (int rg = 0; rg < 4; ++rg) part[rg] += cacc[rg] * wp;
    }
#pragma unroll
    for (int rg = 0; rg < 4; ++rg) red[(wave * 16 + quad * 4 + rg) * 16 + lr] = part[rg];
    __syncthreads();
    if (tid < 64) {
        float s = 0.0f;
#pragma unroll
        for (int q = 0; q < 16; ++q) s += red[tid * 16 + q];
        if (m == 0) s += 17.0f * bprj[0];
        atomicAdd(out + b * 64 + tid, s);
    }
}

// ---------------------------------------------------------------------------
extern "C" void kernel_launch(void* const* d_in, const int* in_sizes, int n_in,
                              void* d_out, int out_size, void* d_ws, size_t ws_size,
                              hipStream_t stream)
{
    const float* node_input       = (const float*)d_in[0];
    const float* node_hidden      = (const float*)d_in[1];
    const float* neighbors_input  = (const float*)d_in[2];
    const float* neighbors_hidden = (const float*)d_in[3];
    const float* Wih_node = (const float*)d_in[5];
    const float* Whh_node = (const float*)d_in[6];
    const float* bih_node = (const float*)d_in[7];
    const float* bhh_node = (const float*)d_in[8];
    const float* Wih_ngh  = (const float*)d_in[9];
    const float* Whh_ngh  = (const float*)d_in[10];
    const float* bih_ngh  = (const float*)d_in[11];
    const float* bhh_ngh  = (const float*)d_in[12];
    const float* Wq   = (const float*)d_in[13];
    const float* Wk   = (const float*)d_in[14];
    const float* Wv   = (const float*)d_in[15];
    const float* Wbil = (const float*)d_in[16];
    const float* bbil = (const float*)d_in[17];
    const float* Wprj = (const float*)d_in[18];
    const float* bprj = (const float*)d_in[19];

    float* out         = (float*)d_out;          // (B,T)     4096
    float* out_node_hT = out + 4096;             // (1,B,H)   16384
    float* out_ngh_hT  = out + 20480;            // (1,B*N,H) 262144
    float* out_A       = out + 282624;           // (B,17,T,T)

    // ---- workspace layout (bytes) ----
    char* w = (char*)d_ws;
    float*          wqb_f    = (float*)(w);                      // 262144 B
    __hip_bfloat16* Wih_n_sw = (__hip_bfloat16*)(w + 262144);    // 196608
    __hip_bfloat16* Wih_g_sw = (__hip_bfloat16*)(w + 458752);    // 196608
    __hip_bfloat16* Whh_n_sw = (__hip_bfloat16*)(w + 655360);    // 393216
    __hip_bfloat16* Whh_g_sw = (__hip_bfloat16*)(w + 1048576);   // 393216
    __hip_bfloat16* Wk_sw    = (__hip_bfloat16*)(w + 1441792);   // 131072
    __hip_bfloat16* Wv_sw    = (__hip_bfloat16*)(w + 1572864);   // 131072
    __hip_bfloat16* wqb_sw   = (__hip_bfloat16*)(w + 1703936);   // 131072
    __hip_bfloat16* node_out_b = (__hip_bfloat16*)(w + 1835008); // 2097152
    __hip_bfloat16* ngh_out_b  = (__hip_bfloat16*)(w + 3932160); // 33554432
    __hip_bfloat16* qb_b       = (__hip_bfloat16*)(w + 37486592);// 2097152
    __hip_bfloat16* gi         = (__hip_bfloat16*)(w + 39583744);// 106954752
    __hip_bfloat16* kbuf = gi;                      // reuse gi region after scan
    __hip_bfloat16* vtbuf = kbuf + 17825792;        // 69632*256 each
    // end: 146538496 B

    hipMemsetAsync(d_out, 0, 4096 * sizeof(float), stream);

    wqb_gemm<<<dim3(4, 4), 256, 0, stream>>>(Wbil, Wq, wqb_f);

    convert_swizzle<<<384, 256, 0, stream>>>(Wih_node, Wih_n_sw, 768, 128);
    convert_swizzle<<<384, 256, 0, stream>>>(Wih_ngh,  Wih_g_sw, 768, 128);
    convert_swizzle<<<768, 256, 0, stream>>>(Whh_node, Whh_n_sw, 768, 256);
    convert_swizzle<<<768, 256, 0, stream>>>(Whh_ngh,  Whh_g_sw, 768, 256);
    convert_swizzle<<<256, 256, 0, stream>>>(Wk,    Wk_sw,  256, 256);
    convert_swizzle<<<256, 256, 0, stream>>>(Wv,    Wv_sw,  256, 256);
    convert_swizzle<<<256, 256, 0, stream>>>(wqb_f, wqb_sw, 256, 256);

    // gi = x @ Wih^T + bih (both GRUs), bf16
    mfma_gemm<<<dim3(1088, 6), 256, 0, stream>>>(
        node_input, neighbors_input, 4096, 1,
        Wih_n_sw, Wih_g_sw, bih_node, bih_ngh,
        gi, 768, 128, 0);

    // weight-stationary persistent GRU scan
    scan_kernel<<<68, 512, 0, stream>>>(gi, Whh_n_sw, Whh_g_sw,
        bhh_node, bhh_ngh, node_hidden, neighbors_hidden,
        node_out_b, ngh_out_b, out_node_hT, out_ngh_hT);

    // K (kv slot layout), V (transposed layout), Qb
    mfma_gemm<<<dim3(1088, 2), 256, 0, stream>>>(
        node_out_b, ngh_out_b, 4096, 0, Wk_sw, Wk_sw, nullptr, nullptr,
        kbuf, 256, 256, 1);
    mfma_gemm<<<dim3(1088, 2), 256, 0, stream>>>(
        node_out_b, ngh_out_b, 4096, 0, Wv_sw, Wv_sw, nullptr, nullptr,
        vtbuf, 256, 256, 2);
    mfma_gemm<<<dim3(64, 2), 256, 0, stream>>>(
        node_out_b, node_out_b, 1 << 30, 0, wqb_sw, wqb_sw, nullptr, nullptr,
        qb_b, 256, 256, 0);

    // fused attention
    attn_kernel<<<1088, 256, 0, stream>>>(qb_b, kbuf, vtbuf, bbil, Wprj, bprj,
                                          out_A, out);
}

// Round 4
// 563.768 us; speedup vs baseline: 4.6304x; 1.0516x over previous
//
#include <hip/hip_runtime.h>
#include <hip/hip_bf16.h>

#define NEGV -1e30f
typedef __attribute__((ext_vector_type(8))) short bf16x8;
typedef __attribute__((ext_vector_type(4))) float f32x4;

__device__ __forceinline__ float sigmoidf_(float x) { return 1.0f / (1.0f + __expf(-x)); }
__device__ __forceinline__ float tanhf_(float x) {
    float ax = fabsf(x);
    float e = __expf(-2.0f * ax);
    float t = (1.0f - e) / (1.0f + e);
    return copysignf(t, x);
}
__device__ __forceinline__ float bf2f(unsigned short u) {
    union { float f; unsigned int i; } x; x.i = ((unsigned int)u) << 16; return x.f;
}

// ---------------------------------------------------------------------------
// wqb_t[h'][d] = sum_k Wbil[k][h'] * Wq[k][d]   (256x256 fp32)
// ---------------------------------------------------------------------------
__global__ __launch_bounds__(256) void wqb_gemm(const float* __restrict__ Wbil_,
    const float* __restrict__ Wq_, float* __restrict__ outw)
{
    __shared__ __align__(16) float As[32 * 68];
    __shared__ __align__(16) float Bs[32 * 68];
    const int tid = threadIdx.x, tx = tid & 15, ty = tid >> 4;
    const int rb = blockIdx.x * 64, cb = blockIdx.y * 64;
    float acc[4][4] = {};
    for (int k0 = 0; k0 < 256; k0 += 32) {
        __syncthreads();
        for (int f = tid; f < 2048; f += 256) {
            int kk = f >> 6, r = f & 63;
            As[kk * 68 + r] = Wbil_[(size_t)(k0 + kk) * 256 + rb + r];
        }
        for (int f = tid; f < 2048; f += 256) {
            int kk = f >> 6, c = f & 63;
            Bs[kk * 68 + c] = Wq_[(size_t)(k0 + kk) * 256 + cb + c];
        }
        __syncthreads();
#pragma unroll
        for (int kk = 0; kk < 32; ++kk) {
            float4 a4 = *(const float4*)(As + kk * 68 + ty * 4);
            float4 b4 = *(const float4*)(Bs + kk * 68 + tx * 4);
            float av[4] = {a4.x, a4.y, a4.z, a4.w};
            float bv[4] = {b4.x, b4.y, b4.z, b4.w};
#pragma unroll
            for (int i = 0; i < 4; ++i)
#pragma unroll
                for (int j = 0; j < 4; ++j) acc[i][j] += av[i] * bv[j];
        }
    }
#pragma unroll
    for (int i = 0; i < 4; ++i)
#pragma unroll
        for (int j = 0; j < 4; ++j)
            outw[(size_t)(rb + ty * 4 + i) * 256 + cb + tx * 4 + j] = acc[i][j];
}

// ---------------------------------------------------------------------------
// One-launch conversion of all weights to bf16 MFMA-B swizzled layout:
// (n,k) -> [((nt*(K/32)+kt)*64 + quad*16 + (n&15))*8 + (k&7)]
// ---------------------------------------------------------------------------
__device__ __forceinline__ void swz_store(const float* __restrict__ src,
    __hip_bfloat16* __restrict__ dst, int idx, int kshift)
{
    int n = idx >> kshift, k = idx & ((1 << kshift) - 1);
    int nt = n >> 4, kt = k >> 5, quad = (k & 31) >> 3, pos = k & 7;
    dst[((size_t)((nt << (kshift - 5)) + kt) * 64 + quad * 16 + (n & 15)) * 8 + pos] =
        (__hip_bfloat16)src[idx];
}

__global__ __launch_bounds__(256) void convert_all(
    const float* __restrict__ Wih_n, const float* __restrict__ Wih_g,
    const float* __restrict__ Whh_n, const float* __restrict__ Whh_g,
    const float* __restrict__ Wk_,   const float* __restrict__ Wv_,
    const float* __restrict__ wqb_f,
    __hip_bfloat16* Wih_n_sw, __hip_bfloat16* Wih_g_sw,
    __hip_bfloat16* Whh_n_sw, __hip_bfloat16* Whh_g_sw,
    __hip_bfloat16* Wk_sw, __hip_bfloat16* Wv_sw, __hip_bfloat16* wqb_sw)
{
    int g = blockIdx.x * 256 + threadIdx.x;
    if (g < 98304)        swz_store(Wih_n, Wih_n_sw, g, 7);
    else if (g < 196608)  swz_store(Wih_g, Wih_g_sw, g - 98304, 7);
    else if (g < 393216)  swz_store(Whh_n, Whh_n_sw, g - 196608, 8);
    else if (g < 589824)  swz_store(Whh_g, Whh_g_sw, g - 393216, 8);
    else if (g < 655360)  swz_store(Wk_,   Wk_sw,   g - 589824, 8);
    else if (g < 720896)  swz_store(Wv_,   Wv_sw,   g - 655360, 8);
    else                  swz_store(wqb_f, wqb_sw,  g - 720896, 8);
}

// ---------------------------------------------------------------------------
// gi = x @ Wih^T + bih, all 768 output cols per block (A staged once).
// 1088 blocks x 256 threads; wave w owns rows w*16..+15, loops 48 n-tiles.
// ---------------------------------------------------------------------------
__global__ __launch_bounds__(256) void gi_gemm(
    const float* __restrict__ A0, const float* __restrict__ A1,
    const __hip_bfloat16* __restrict__ W0, const __hip_bfloat16* __restrict__ W1,
    const float* __restrict__ b0, const float* __restrict__ b1,
    __hip_bfloat16* __restrict__ C)
{
    __shared__ __align__(16) __hip_bfloat16 As[64 * 136];
    const int tid = threadIdx.x, wave = tid >> 6, lane = tid & 63;
    const int quad = lane >> 4, lr = lane & 15;
    const int rb = blockIdx.x * 64;
    const bool node = rb < 4096;
    const float* A = node ? (A0 + (size_t)rb * 128) : (A1 + (size_t)(rb - 4096) * 128);
    const __hip_bfloat16* W = node ? W0 : W1;
    const float* bias = node ? b0 : b1;

    for (int f = tid; f < 1024; f += 256) {
        int row = f >> 4, cc = (f & 15) * 8;
        const float* Af = A + (size_t)row * 128 + cc;
        float4 v0 = *(const float4*)Af;
        float4 v1 = *(const float4*)(Af + 4);
        __hip_bfloat16* d = As + row * 136 + cc;
        d[0] = (__hip_bfloat16)v0.x; d[1] = (__hip_bfloat16)v0.y;
        d[2] = (__hip_bfloat16)v0.z; d[3] = (__hip_bfloat16)v0.w;
        d[4] = (__hip_bfloat16)v1.x; d[5] = (__hip_bfloat16)v1.y;
        d[6] = (__hip_bfloat16)v1.z; d[7] = (__hip_bfloat16)v1.w;
    }
    __syncthreads();

    bf16x8 afr[4];
#pragma unroll
    for (int kt = 0; kt < 4; ++kt)
        afr[kt] = *(const bf16x8*)(const void*)(As + (wave * 16 + lr) * 136 + kt * 32 + quad * 8);

    const int r0 = rb + wave * 16 + quad * 4;
    for (int ntg = 0; ntg < 48; ++ntg) {
        f32x4 acc = {0.f, 0.f, 0.f, 0.f};
#pragma unroll
        for (int kt = 0; kt < 4; ++kt) {
            bf16x8 bfr = *(const bf16x8*)(const void*)(W + ((size_t)(ntg * 4 + kt) * 64 + lane) * 8);
            acc = __builtin_amdgcn_mfma_f32_16x16x32_bf16(afr[kt], bfr, acc, 0, 0, 0);
        }
        int col = ntg * 16 + lr;
        float bv = bias[col];
#pragma unroll
        for (int rg = 0; rg < 4; ++rg)
            C[(size_t)(r0 + rg) * 768 + col] = (__hip_bfloat16)(acc[rg] + bv);
    }
}

// ---------------------------------------------------------------------------
// Weight-stationary persistent GRU scan. 68 blocks x 256 threads (4 waves,
// 1 wave/SIMD, __launch_bounds__(256,1) -> up to 512 VGPR/wave). Wave owns
// 12 n-tiles: wreg[96] bf16x8 = 384 VGPR held across all 64 steps. fp32 h
// master in registers (16/thread); bf16 h A-fragments in LDS.
// ---------------------------------------------------------------------------
__global__ __launch_bounds__(256, 1) void scan_kernel(
    const __hip_bfloat16* __restrict__ gi,
    const __hip_bfloat16* __restrict__ Whh_n_sw,
    const __hip_bfloat16* __restrict__ Whh_g_sw,
    const float* __restrict__ bhh_node, const float* __restrict__ bhh_ngh,
    const float* __restrict__ node_hidden, const float* __restrict__ neighbors_hidden,
    __hip_bfloat16* __restrict__ node_out, __hip_bfloat16* __restrict__ ngh_out,
    float* __restrict__ out_node_hT, float* __restrict__ out_ngh_hT)
{
    __shared__ __align__(16) __hip_bfloat16 gh_b[16 * 776];
    __shared__ __align__(16) __hip_bfloat16 h_frag[8 * 64 * 8];
    __shared__ float bhh_l[768];
    const int tid = threadIdx.x;
    const int wave = tid >> 6, lane = tid & 63;
    const int quad = lane >> 4, lr = lane & 15;
    const int row0 = blockIdx.x * 16;
    const bool isnode = (row0 < 64);
    const __hip_bfloat16* Wsw = isnode ? Whh_n_sw : Whh_g_sw;
    const float* bhh = isnode ? bhh_node : bhh_ngh;
    // pointwise mapping: 16 elems per thread
    const int pr = tid >> 4;            // 0..15
    const int pc0 = (tid & 15) * 16;    // 0..240
    const int grow = row0 + pr;
    const size_t gibase = isnode ? ((size_t)grow * 64) : (4096 + (size_t)(grow - 64) * 64);
    // h_frag offset of element (pr, pc0): two contiguous 8-chunks, second +128
    const int fragoff = ((pc0 >> 5) * 64 + ((pc0 & 31) >> 3) * 16 + pr) * 8;
    __hip_bfloat16* orow_base = isnode
        ? (node_out + ((size_t)grow * 64) * 256 + pc0)
        : (ngh_out + ((size_t)(grow - 64) * 64) * 256 + pc0);

    // ---- stationary weights: 96 fragments (384 VGPR/lane)
    bf16x8 wreg[96];
#pragma unroll
    for (int nt = 0; nt < 12; ++nt)
#pragma unroll
        for (int kt = 0; kt < 8; ++kt)
            wreg[nt * 8 + kt] = *(const bf16x8*)(const void*)(
                Wsw + ((size_t)((wave * 12 + nt) * 8 + kt) * 64 + lane) * 8);

    for (int f = tid; f < 768; f += 256) bhh_l[f] = bhh[f];

    // ---- h0 -> fp32 register master + bf16 fragment LDS
    float hm[16];
    {
        const float* src = isnode ? (node_hidden + (size_t)row0 * 256)
                                  : (neighbors_hidden + (size_t)(row0 - 64) * 256);
        const float* sp = src + (size_t)pr * 256 + pc0;
        __hip_bfloat16 hb[16];
#pragma unroll
        for (int c = 0; c < 4; ++c) {
            float4 v = *(const float4*)(sp + c * 4);
            hm[c * 4 + 0] = v.x; hm[c * 4 + 1] = v.y;
            hm[c * 4 + 2] = v.z; hm[c * 4 + 3] = v.w;
        }
#pragma unroll
        for (int jj = 0; jj < 16; ++jj) hb[jj] = (__hip_bfloat16)hm[jj];
        *(uint4*)(void*)(h_frag + fragoff)       = *(const uint4*)(const void*)hb;
        *(uint4*)(void*)(h_frag + fragoff + 128) = *(const uint4*)(const void*)(hb + 8);
    }
    __syncthreads();

    for (int t = 0; t < 64; ++t) {
        // ---- MFMA: gh = h @ Whh^T (zero global/LDS weight traffic)
        f32x4 acc[12];
#pragma unroll
        for (int nt = 0; nt < 12; ++nt) acc[nt] = (f32x4){0.f, 0.f, 0.f, 0.f};
#pragma unroll
        for (int kt = 0; kt < 8; ++kt) {
            bf16x8 afr = *(const bf16x8*)(const void*)(h_frag + (kt * 64 + lane) * 8);
#pragma unroll
            for (int nt = 0; nt < 12; ++nt)
                acc[nt] = __builtin_amdgcn_mfma_f32_16x16x32_bf16(afr, wreg[nt * 8 + kt], acc[nt], 0, 0, 0);
        }
#pragma unroll
        for (int nt = 0; nt < 12; ++nt) {
            int col = (wave * 12 + nt) * 16 + lr;
#pragma unroll
            for (int rg = 0; rg < 4; ++rg)
                gh_b[(quad * 4 + rg) * 776 + col] = (__hip_bfloat16)acc[nt][rg];
        }
        __syncthreads();

        // ---- pointwise gates, 16 elems/thread
        {
            const __hip_bfloat16* g = gi + (gibase + t) * 768;
            bf16x8 gr[2], gz[2], gn[2], Gr[2], Gz[2], Gn[2];
#pragma unroll
            for (int c = 0; c < 2; ++c) {
                gr[c] = *(const bf16x8*)(const void*)(g + pc0 + c * 8);
                gz[c] = *(const bf16x8*)(const void*)(g + 256 + pc0 + c * 8);
                gn[c] = *(const bf16x8*)(const void*)(g + 512 + pc0 + c * 8);
                Gr[c] = *(const bf16x8*)(const void*)(gh_b + pr * 776 + pc0 + c * 8);
                Gz[c] = *(const bf16x8*)(const void*)(gh_b + pr * 776 + 256 + pc0 + c * 8);
                Gn[c] = *(const bf16x8*)(const void*)(gh_b + pr * 776 + 512 + pc0 + c * 8);
            }
            __hip_bfloat16 hb[16];
#pragma unroll
            for (int c = 0; c < 2; ++c)
#pragma unroll
                for (int jj = 0; jj < 8; ++jj) {
                    int j = pc0 + c * 8 + jj;
                    int e = c * 8 + jj;
                    float ghr = bf2f((unsigned short)Gr[c][jj]) + bhh_l[j];
                    float ghz = bf2f((unsigned short)Gz[c][jj]) + bhh_l[256 + j];
                    float ghn = bf2f((unsigned short)Gn[c][jj]) + bhh_l[512 + j];
                    float rg_ = sigmoidf_(bf2f((unsigned short)gr[c][jj]) + ghr);
                    float zg  = sigmoidf_(bf2f((unsigned short)gz[c][jj]) + ghz);
                    float ng  = tanhf_(bf2f((unsigned short)gn[c][jj]) + rg_ * ghn);
                    float hn = (1.0f - zg) * ng + zg * hm[e];
                    hm[e] = hn;
                    hb[e] = (__hip_bfloat16)hn;
                }
            *(uint4*)(void*)(h_frag + fragoff)       = *(const uint4*)(const void*)hb;
            *(uint4*)(void*)(h_frag + fragoff + 128) = *(const uint4*)(const void*)(hb + 8);
            __hip_bfloat16* orow = orow_base + (size_t)t * 256;
            *(uint4*)(void*)(orow)     = *(const uint4*)(const void*)hb;
            *(uint4*)(void*)(orow + 8) = *(const uint4*)(const void*)(hb + 8);
        }
        __syncthreads();
    }

    // ---- final hidden states fp32
    {
        float* dst = isnode ? (out_node_hT + (size_t)row0 * 256)
                            : (out_ngh_hT + (size_t)(row0 - 64) * 256);
        float* dp = dst + (size_t)pr * 256 + pc0;
#pragma unroll
        for (int c = 0; c < 4; ++c) {
            float4 v = {hm[c * 4 + 0], hm[c * 4 + 1], hm[c * 4 + 2], hm[c * 4 + 3]};
            *(float4*)(dp + c * 4) = v;
        }
    }
}

// ---------------------------------------------------------------------------
// Fused K/V(+Qb for node rows) GEMM. 1088 blocks x 256 threads; A (64x256
// bf16) staged once; wave w owns rows w*16..+15; loops n-tiles for K, V^T,
// and (node blocks only) Qb.
// ---------------------------------------------------------------------------
__global__ __launch_bounds__(256) void kv_gemm(
    const __hip_bfloat16* __restrict__ A0, const __hip_bfloat16* __restrict__ A1,
    const __hip_bfloat16* __restrict__ Wk_sw, const __hip_bfloat16* __restrict__ Wv_sw,
    const __hip_bfloat16* __restrict__ wqb_sw,
    __hip_bfloat16* __restrict__ Kb, __hip_bfloat16* __restrict__ Vt,
    __hip_bfloat16* __restrict__ Qb)
{
    __shared__ __align__(16) __hip_bfloat16 As[64 * 264];
    const int tid = threadIdx.x, wave = tid >> 6, lane = tid & 63;
    const int quad = lane >> 4, lr = lane & 15;
    const int rb = blockIdx.x * 64;
    const bool node = rb < 4096;
    const __hip_bfloat16* A = node ? (A0 + (size_t)rb * 256) : (A1 + (size_t)(rb - 4096) * 256);

    for (int f = tid; f < 2048; f += 256) {
        int row = f >> 5, cc = (f & 31) * 8;
        *(uint4*)(void*)(As + row * 264 + cc) =
            *(const uint4*)(const void*)(A + (size_t)row * 256 + cc);
    }
    __syncthreads();

    bf16x8 afr[8];
#pragma unroll
    for (int kt = 0; kt < 8; ++kt)
        afr[kt] = *(const bf16x8*)(const void*)(As + (wave * 16 + lr) * 264 + kt * 32 + quad * 8);

    int b_, slot;
    if (node) { b_ = rb >> 6; slot = 0; }
    else { int rr = (rb - 4096) >> 6; b_ = rr >> 4; slot = (rr & 15) + 1; }
    const size_t kbase = ((size_t)b_ * 1088 + slot * 64) * 256;
    const size_t vtbase = (size_t)(b_ * 17 + slot) * 256 * 64;
    const int s0 = wave * 16 + quad * 4;

    // K
    for (int ntg = 0; ntg < 16; ++ntg) {
        f32x4 acc = {0.f, 0.f, 0.f, 0.f};
#pragma unroll
        for (int kt = 0; kt < 8; ++kt) {
            bf16x8 bfr = *(const bf16x8*)(const void*)(Wk_sw + ((size_t)(ntg * 8 + kt) * 64 + lane) * 8);
            acc = __builtin_amdgcn_mfma_f32_16x16x32_bf16(afr[kt], bfr, acc, 0, 0, 0);
        }
        int col = ntg * 16 + lr;
#pragma unroll
        for (int rg = 0; rg < 4; ++rg)
            Kb[kbase + (size_t)(s0 + rg) * 256 + col] = (__hip_bfloat16)acc[rg];
    }
    // V (transposed store)
    for (int ntg = 0; ntg < 16; ++ntg) {
        f32x4 acc = {0.f, 0.f, 0.f, 0.f};
#pragma unroll
        for (int kt = 0; kt < 8; ++kt) {
            bf16x8 bfr = *(const bf16x8*)(const void*)(Wv_sw + ((size_t)(ntg * 8 + kt) * 64 + lane) * 8);
            acc = __builtin_amdgcn_mfma_f32_16x16x32_bf16(afr[kt], bfr, acc, 0, 0, 0);
        }
        int col = ntg * 16 + lr;
        __hip_bfloat16 t4[4];
#pragma unroll
        for (int rg = 0; rg < 4; ++rg) t4[rg] = (__hip_bfloat16)acc[rg];
        *(uint2*)(void*)(Vt + vtbase + (size_t)col * 64 + s0) = *(const uint2*)(const void*)t4;
    }
    // Qb (node rows only)
    if (node) {
        for (int ntg = 0; ntg < 16; ++ntg) {
            f32x4 acc = {0.f, 0.f, 0.f, 0.f};
#pragma unroll
            for (int kt = 0; kt < 8; ++kt) {
                bf16x8 bfr = *(const bf16x8*)(const void*)(wqb_sw + ((size_t)(ntg * 8 + kt) * 64 + lane) * 8);
                acc = __builtin_amdgcn_mfma_f32_16x16x32_bf16(afr[kt], bfr, acc, 0, 0, 0);
            }
            int col = ntg * 16 + lr;
#pragma unroll
            for (int rg = 0; rg < 4; ++rg)
                Qb[(size_t)(rb + s0 + rg) * 256 + col] = (__hip_bfloat16)acc[rg];
        }
    }
}

// ---------------------------------------------------------------------------
// Fused attention per (b,m), MFMA-based (unchanged from round 3, validated).
// ---------------------------------------------------------------------------
__global__ __launch_bounds__(256) void attn_kernel(
    const __hip_bfloat16* __restrict__ Qb, const __hip_bfloat16* __restrict__ Kb,
    const __hip_bfloat16* __restrict__ Vt, const float* __restrict__ bbil,
    const float* __restrict__ Wprj, const float* __restrict__ bprj,
    float* __restrict__ A_out, float* __restrict__ out)
{
    __shared__ __align__(16) float Sbuf[64 * 68];
    __shared__ __align__(16) __hip_bfloat16 Pb[64 * 72];
    __shared__ float rowmax[64], rowrcp[64];
    __shared__ float red[64 * 16];
    const int tid = threadIdx.x;
    const int wave = tid >> 6, lane = tid & 63;
    const int quad = lane >> 4, lr = lane & 15;
    const int bm = blockIdx.x, b = bm / 17, m = bm % 17;
    const __hip_bfloat16* Qrow = Qb + (size_t)b * 64 * 256;
    const __hip_bfloat16* Krow = Kb + ((size_t)b * 1088 + m * 64) * 256;
    const __hip_bfloat16* Vtrow = Vt + (size_t)(b * 17 + m) * 256 * 64;

    f32x4 sacc[4] = {{0.f,0.f,0.f,0.f},{0.f,0.f,0.f,0.f},{0.f,0.f,0.f,0.f},{0.f,0.f,0.f,0.f}};
#pragma unroll
    for (int kt = 0; kt < 8; ++kt) {
        bf16x8 afr = *(const bf16x8*)(const void*)(Qrow + (size_t)(wave * 16 + lr) * 256 + kt * 32 + quad * 8);
#pragma unroll
        for (int c = 0; c < 4; ++c) {
            bf16x8 bfr = *(const bf16x8*)(const void*)(Krow + (size_t)(c * 16 + lr) * 256 + kt * 32 + quad * 8);
            sacc[c] = __builtin_amdgcn_mfma_f32_16x16x32_bf16(afr, bfr, sacc[c], 0, 0, 0);
        }
    }
#pragma unroll
    for (int c = 0; c < 4; ++c)
#pragma unroll
        for (int rg = 0; rg < 4; ++rg) {
            int t_ = wave * 16 + quad * 4 + rg, s_ = c * 16 + lr;
            Sbuf[t_ * 68 + s_] = (s_ <= t_) ? (sacc[c][rg] + bbil[s_]) : NEGV;
        }
    __syncthreads();
    if (tid < 64) {
        float mx = -3.0e38f;
        for (int s = 0; s < 64; ++s) mx = fmaxf(mx, Sbuf[tid * 68 + s]);
        float sum = 0.0f;
        for (int s = 0; s < 64; ++s) sum += __expf(Sbuf[tid * 68 + s] - mx);
        rowmax[tid] = mx;
        rowrcp[tid] = 1.0f / sum;
    }
    __syncthreads();
    for (int idx = tid; idx < 4096; idx += 256) {
        int t_ = idx >> 6, s_ = idx & 63;
        float e = __expf(Sbuf[t_ * 68 + s_] - rowmax[t_]) * rowrcp[t_];
        A_out[(size_t)bm * 4096 + idx] = e;
        Pb[t_ * 72 + s_] = (__hip_bfloat16)e;
    }
    __syncthreads();

    bf16x8 pfr[2];
#pragma unroll
    for (int k2 = 0; k2 < 2; ++k2)
        pfr[k2] = *(const bf16x8*)(const void*)(Pb + (wave * 16 + lr) * 72 + k2 * 32 + quad * 8);
    float part[4] = {0.f, 0.f, 0.f, 0.f};
#pragma unroll
    for (int nt = 0; nt < 16; ++nt) {
        f32x4 cacc = {0.f, 0.f, 0.f, 0.f};
#pragma unroll
        for (int k2 = 0; k2 < 2; ++k2) {
            bf16x8 bfr = *(const bf16x8*)(const void*)(Vtrow + (size_t)(nt * 16 + lr) * 64 + k2 * 32 + quad * 8);
            cacc = __builtin_amdgcn_mfma_f32_16x16x32_bf16(pfr[k2], bfr, cacc, 0, 0, 0);
        }
        float wp = Wprj[nt * 16 + lr];
#pragma unroll
        for (int rg = 0; rg < 4; ++rg) part[rg] += cacc[rg] * wp;
    }
#pragma unroll
    for (int rg = 0; rg < 4; ++rg) red[(wave * 16 + quad * 4 + rg) * 16 + lr] = part[rg];
    __syncthreads();
    if (tid < 64) {
        float s = 0.0f;
#pragma unroll
        for (int q = 0; q < 16; ++q) s += red[tid * 16 + q];
        if (m == 0) s += 17.0f * bprj[0];
        atomicAdd(out + b * 64 + tid, s);
    }
}

// ---------------------------------------------------------------------------
extern "C" void kernel_launch(void* const* d_in, const int* in_sizes, int n_in,
                              void* d_out, int out_size, void* d_ws, size_t ws_size,
                              hipStream_t stream)
{
    const float* node_input       = (const float*)d_in[0];
    const float* node_hidden      = (const float*)d_in[1];
    const float* neighbors_input  = (const float*)d_in[2];
    const float* neighbors_hidden = (const float*)d_in[3];
    const float* Wih_node = (const float*)d_in[5];
    const float* Whh_node = (const float*)d_in[6];
    const float* bih_node = (const float*)d_in[7];
    const float* bhh_node = (const float*)d_in[8];
    const float* Wih_ngh  = (const float*)d_in[9];
    const float* Whh_ngh  = (const float*)d_in[10];
    const float* bih_ngh  = (const float*)d_in[11];
    const float* bhh_ngh  = (const float*)d_in[12];
    const float* Wq   = (const float*)d_in[13];
    const float* Wk   = (const float*)d_in[14];
    const float* Wv   = (const float*)d_in[15];
    const float* Wbil = (const float*)d_in[16];
    const float* bbil = (const float*)d_in[17];
    const float* Wprj = (const float*)d_in[18];
    const float* bprj = (const float*)d_in[19];

    float* out         = (float*)d_out;          // (B,T)     4096
    float* out_node_hT = out + 4096;             // (1,B,H)   16384
    float* out_ngh_hT  = out + 20480;            // (1,B*N,H) 262144
    float* out_A       = out + 282624;           // (B,17,T,T)

    // ---- workspace layout (bytes) ----
    char* w = (char*)d_ws;
    float*          wqb_f    = (float*)(w);                      // 262144 B
    __hip_bfloat16* Wih_n_sw = (__hip_bfloat16*)(w + 262144);    // 196608
    __hip_bfloat16* Wih_g_sw = (__hip_bfloat16*)(w + 458752);    // 196608
    __hip_bfloat16* Whh_n_sw = (__hip_bfloat16*)(w + 655360);    // 393216
    __hip_bfloat16* Whh_g_sw = (__hip_bfloat16*)(w + 1048576);   // 393216
    __hip_bfloat16* Wk_sw    = (__hip_bfloat16*)(w + 1441792);   // 131072
    __hip_bfloat16* Wv_sw    = (__hip_bfloat16*)(w + 1572864);   // 131072
    __hip_bfloat16* wqb_sw   = (__hip_bfloat16*)(w + 1703936);   // 131072
    __hip_bfloat16* node_out_b = (__hip_bfloat16*)(w + 1835008); // 2097152
    __hip_bfloat16* ngh_out_b  = (__hip_bfloat16*)(w + 3932160); // 33554432
    __hip_bfloat16* qb_b       = (__hip_bfloat16*)(w + 37486592);// 2097152
    __hip_bfloat16* gi         = (__hip_bfloat16*)(w + 39583744);// 106954752
    __hip_bfloat16* kbuf = gi;                      // reuse gi region after scan
    __hip_bfloat16* vtbuf = kbuf + 17825792;        // 69632*256 each
    // end: 146538496 B

    hipMemsetAsync(d_out, 0, 4096 * sizeof(float), stream);

    wqb_gemm<<<dim3(4, 4), 256, 0, stream>>>(Wbil, Wq, wqb_f);

    convert_all<<<3072, 256, 0, stream>>>(
        Wih_node, Wih_ngh, Whh_node, Whh_ngh, Wk, Wv, wqb_f,
        Wih_n_sw, Wih_g_sw, Whh_n_sw, Whh_g_sw, Wk_sw, Wv_sw, wqb_sw);

    gi_gemm<<<1088, 256, 0, stream>>>(
        node_input, neighbors_input, Wih_n_sw, Wih_g_sw, bih_node, bih_ngh, gi);

    scan_kernel<<<68, 256, 0, stream>>>(gi, Whh_n_sw, Whh_g_sw,
        bhh_node, bhh_ngh, node_hidden, neighbors_hidden,
        node_out_b, ngh_out_b, out_node_hT, out_ngh_hT);

    kv_gemm<<<1088, 256, 0, stream>>>(
        node_out_b, ngh_out_b, Wk_sw, Wv_sw, wqb_sw, kbuf, vtbuf, qb_b);

    attn_kernel<<<1088, 256, 0, stream>>>(qb_b, kbuf, vtbuf, bbil, Wprj, bprj,
                                          out_A, out);
}